// Round 1
// 209.727 us; speedup vs baseline: 1.1877x; 1.1877x over previous
//
#include <hip/hip_runtime.h>

#define NB 4
#define NT 40000
#define NS0 30000
#define ND0 15000
#define NE0 360000
#define ND1 7500
#define NE1 180000
#define NEG 0.2f

#define CAP 64                            // bucket capacity per dst (avg deg 24)
#define K1B ((NB*NS0)/64)                 // 1875 GEMM blocks
#define SB  ((NE0 + NE1 + 255)/256)       // 2110 scatter blocks

typedef __attribute__((ext_vector_type(8))) short bf8;
typedef __attribute__((ext_vector_type(4))) float f4;

__device__ __forceinline__ unsigned short f2bf(float f) {
    unsigned u = __float_as_uint(f);
    u += 0x7FFF + ((u >> 16) & 1);          // round-to-nearest-even
    return (unsigned short)(u >> 16);
}
// packed bf16 pair in a uint: low ushort = even channel, high = odd channel
__device__ __forceinline__ float bf_lo(unsigned u) { return __uint_as_float(u << 16); }
__device__ __forceinline__ float bf_hi(unsigned u) { return __uint_as_float(u & 0xFFFF0000u); }

// -------- fused: layer-1 MFMA GEMM + bucket scatter (CSR without scan) -----
// blocks [0, K1B): node transform; blocks [K1B, K1B+SB): edge scatter into
// fixed-capacity (CAP=64) per-dst buckets. pos = atomicAdd(cur[d]) gives the
// slot AND, after the kernel, cur[d] == degree — no histogram, no prefix scan.
__global__ __launch_bounds__(256) void kA_gemm_scat(
        const float* __restrict__ x, const int* __restrict__ n_id0,
        const float* __restrict__ W1, const float* __restrict__ a_src,
        const float* __restrict__ a_dst,
        unsigned short* __restrict__ ht1b, float* __restrict__ es1, float* __restrict__ ed1,
        const int* __restrict__ esrc0, const int* __restrict__ edst0,
        const int* __restrict__ esrc1, const int* __restrict__ edst1,
        int* __restrict__ cur0, int* __restrict__ cur1,
        int* __restrict__ srcsort0, int* __restrict__ srcsort1) {
    __shared__ unsigned short xtb[64*72];
    __shared__ unsigned short wtb[64*72];
    __shared__ float asl[64], adl[64];
    if (blockIdx.x >= K1B) {                 // ---- scatter part ----
        int t = (blockIdx.x - K1B) * 256 + threadIdx.x;
        if (t < NE0) {
            int d = edst0[t];
            int pos = atomicAdd(&cur0[d], 1);
            if (pos < CAP) srcsort0[d*CAP + pos] = esrc0[t];
        } else if (t < NE0 + NE1) {
            int e = t - NE0;
            int d = edst1[e];
            int pos = atomicAdd(&cur1[d], 1);
            if (pos < CAP) srcsort1[d*CAP + pos] = esrc1[e];
        }
        return;
    }
    // ---- GEMM part ----
    int t = threadIdx.x;
    {
        int k = t >> 2, nb = (t & 3) * 16;
        const float* wrow = &W1[k*64 + nb];
        #pragma unroll
        for (int j = 0; j < 16; j += 4) {
            float4 v = *(const float4*)&wrow[j];
            wtb[(nb+j+0)*72 + k] = f2bf(v.x);
            wtb[(nb+j+1)*72 + k] = f2bf(v.y);
            wtb[(nb+j+2)*72 + k] = f2bf(v.z);
            wtb[(nb+j+3)*72 + k] = f2bf(v.w);
        }
    }
    if (t < 64) { asl[t] = a_src[t]; adl[t] = a_dst[t]; }
    {
        int rr = t & 63;
        int q4 = t >> 6;
        int row_s = blockIdx.x * 64 + rr;           // < 120000 (1875*64)
        int bs = row_s / NS0;
        int ns = row_s - bs * NS0;
        const float* xrow = x + ((size_t)(bs * NT + n_id0[ns])) * 64;
        #pragma unroll
        for (int j = 0; j < 4; ++j) {
            int k = q4 * 16 + j * 4;
            float4 v = *(const float4*)&xrow[k];
            ushort4 u;
            u.x = f2bf(v.x); u.y = f2bf(v.y); u.z = f2bf(v.z); u.w = f2bf(v.w);
            *(ushort4*)&xtb[rr*72 + k] = u;
        }
    }
    __syncthreads();
    int w = t >> 6, lane = t & 63, quad = lane >> 4, cl = lane & 15;
    int arow = 16*w + cl;
    bf8 a0 = *(const bf8*)&xtb[arow*72 + quad*8];        // A[m=cl][k=quad*8+j]
    bf8 a1 = *(const bf8*)&xtb[arow*72 + 32 + quad*8];   // k+32
    f4 acc[4];
    #pragma unroll
    for (int sub = 0; sub < 4; ++sub) {
        int n = sub*16 + cl;
        bf8 b0 = *(const bf8*)&wtb[n*72 + quad*8];       // B[k][n=cl]
        bf8 b1 = *(const bf8*)&wtb[n*72 + 32 + quad*8];
        f4 c = {0.f, 0.f, 0.f, 0.f};
        c = __builtin_amdgcn_mfma_f32_16x16x32_bf16(a0, b0, c, 0, 0, 0);
        c = __builtin_amdgcn_mfma_f32_16x16x32_bf16(a1, b1, c, 0, 0, 0);
        acc[sub] = c;
    }
    int rbase = blockIdx.x*64 + 16*w + quad*4;
    #pragma unroll
    for (int sub = 0; sub < 4; ++sub)
        #pragma unroll
        for (int r = 0; r < 4; ++r)
            ht1b[(size_t)(rbase + r)*64 + sub*16 + cl] = f2bf(acc[sub][r]);
    #pragma unroll
    for (int r = 0; r < 4; ++r) {
        #pragma unroll
        for (int sub = 0; sub < 4; ++sub) {
            int col = sub*16 + cl;
            float ps = acc[sub][r] * asl[col];
            float pd = acc[sub][r] * adl[col];
            ps += __shfl_xor(ps, 1); ps += __shfl_xor(ps, 2); ps += __shfl_xor(ps, 4);
            pd += __shfl_xor(pd, 1); pd += __shfl_xor(pd, 2); pd += __shfl_xor(pd, 4);
            if ((cl & 7) == 0) {
                int h = sub*2 + (cl >> 3);
                es1[(rbase + r)*8 + h] = ps;
                ed1[(rbase + r)*8 + h] = pd;
            }
        }
    }
}

// ---------------- layer 1 per-dst aggregation ------------------------------
// 1 dst/wave, 8 x 8-lane edge slots, 4-deep branch-free pipeline. Buckets are
// [d*CAP .. d*CAP+cnt); cnt comes straight from cur0 (scatter counter).
__global__ __launch_bounds__(256) void k3_agg1(
        const int* __restrict__ srcsort0, const int* __restrict__ cur0,
        const int* __restrict__ res0,
        const float* __restrict__ es1, const float* __restrict__ ed1,
        const unsigned short* __restrict__ ht1b, const float* __restrict__ b1,
        float* __restrict__ agg1) {
    int b = blockIdx.x / (ND0/4);
    int chunk = blockIdx.x - b * (ND0/4);
    int d = chunk * 4 + (threadIdx.x >> 6);
    int lane = threadIdx.x & 63;
    int grp = lane >> 3;                   // edge slot 0..7
    int c = lane & 7;                      // head index; channels 8c..8c+7
    int dn = res0[d];
    float edv = ed1[(b*NS0 + dn)*8 + c];
    int start = d * CAP;
    int cnt = cur0[d];
    const float* esb = es1 + (size_t)b*NS0*8;
    const unsigned short* htb = ht1b + (size_t)b*NS0*64;
    float acc[8] = {};
    float wsum = 0.f;
    int i = grp;
    bool v0 = i      < cnt, v1 = i + 8  < cnt,
         v2 = i + 16 < cnt, v3 = i + 24 < cnt;
    int s0 = v0 ? srcsort0[start + i]      : 0;
    int s1 = v1 ? srcsort0[start + i + 8]  : 0;
    int s2 = v2 ? srcsort0[start + i + 16] : 0;
    int s3 = v3 ? srcsort0[start + i + 24] : 0;
    for (;;) {
        float e0 = esb[s0*8 + c], e1 = esb[s1*8 + c];
        float e2 = esb[s2*8 + c], e3 = esb[s3*8 + c];
        uint4 h0 = *(const uint4*)&htb[(size_t)s0*64 + c*8];
        uint4 h1 = *(const uint4*)&htb[(size_t)s1*64 + c*8];
        uint4 h2 = *(const uint4*)&htb[(size_t)s2*64 + c*8];
        uint4 h3 = *(const uint4*)&htb[(size_t)s3*64 + c*8];
        int ni = i + 32;
        bool nv0 = ni      < cnt, nv1 = ni + 8  < cnt,
             nv2 = ni + 16 < cnt, nv3 = ni + 24 < cnt;
        int t0 = nv0 ? srcsort0[start + ni]      : 0;
        int t1 = nv1 ? srcsort0[start + ni + 8]  : 0;
        int t2 = nv2 ? srcsort0[start + ni + 16] : 0;
        int t3 = nv3 ? srcsort0[start + ni + 24] : 0;
        e0 += edv; e1 += edv; e2 += edv; e3 += edv;
        e0 = e0 > 0.f ? e0 : NEG * e0;
        e1 = e1 > 0.f ? e1 : NEG * e1;
        e2 = e2 > 0.f ? e2 : NEG * e2;
        e3 = e3 > 0.f ? e3 : NEG * e3;
        float w0 = v0 ? __expf(e0) : 0.f;
        float w1 = v1 ? __expf(e1) : 0.f;
        float w2 = v2 ? __expf(e2) : 0.f;
        float w3 = v3 ? __expf(e3) : 0.f;
        acc[0] = fmaf(w0, bf_lo(h0.x), acc[0]); acc[1] = fmaf(w0, bf_hi(h0.x), acc[1]);
        acc[2] = fmaf(w0, bf_lo(h0.y), acc[2]); acc[3] = fmaf(w0, bf_hi(h0.y), acc[3]);
        acc[4] = fmaf(w0, bf_lo(h0.z), acc[4]); acc[5] = fmaf(w0, bf_hi(h0.z), acc[5]);
        acc[6] = fmaf(w0, bf_lo(h0.w), acc[6]); acc[7] = fmaf(w0, bf_hi(h0.w), acc[7]);
        acc[0] = fmaf(w1, bf_lo(h1.x), acc[0]); acc[1] = fmaf(w1, bf_hi(h1.x), acc[1]);
        acc[2] = fmaf(w1, bf_lo(h1.y), acc[2]); acc[3] = fmaf(w1, bf_hi(h1.y), acc[3]);
        acc[4] = fmaf(w1, bf_lo(h1.z), acc[4]); acc[5] = fmaf(w1, bf_hi(h1.z), acc[5]);
        acc[6] = fmaf(w1, bf_lo(h1.w), acc[6]); acc[7] = fmaf(w1, bf_hi(h1.w), acc[7]);
        acc[0] = fmaf(w2, bf_lo(h2.x), acc[0]); acc[1] = fmaf(w2, bf_hi(h2.x), acc[1]);
        acc[2] = fmaf(w2, bf_lo(h2.y), acc[2]); acc[3] = fmaf(w2, bf_hi(h2.y), acc[3]);
        acc[4] = fmaf(w2, bf_lo(h2.z), acc[4]); acc[5] = fmaf(w2, bf_hi(h2.z), acc[5]);
        acc[6] = fmaf(w2, bf_lo(h2.w), acc[6]); acc[7] = fmaf(w2, bf_hi(h2.w), acc[7]);
        acc[0] = fmaf(w3, bf_lo(h3.x), acc[0]); acc[1] = fmaf(w3, bf_hi(h3.x), acc[1]);
        acc[2] = fmaf(w3, bf_lo(h3.y), acc[2]); acc[3] = fmaf(w3, bf_hi(h3.y), acc[3]);
        acc[4] = fmaf(w3, bf_lo(h3.z), acc[4]); acc[5] = fmaf(w3, bf_hi(h3.z), acc[5]);
        acc[6] = fmaf(w3, bf_lo(h3.w), acc[6]); acc[7] = fmaf(w3, bf_hi(h3.w), acc[7]);
        wsum += (w0 + w1) + (w2 + w3);
        i = ni; s0 = t0; s1 = t1; s2 = t2; s3 = t3;
        v0 = nv0; v1 = nv1; v2 = nv2; v3 = nv3;
        if (i >= cnt) break;
    }
    #pragma unroll
    for (int j = 0; j < 8; ++j) {
        acc[j] += __shfl_xor(acc[j], 8);
        acc[j] += __shfl_xor(acc[j], 16);
        acc[j] += __shfl_xor(acc[j], 32);
    }
    wsum += __shfl_xor(wsum, 8); wsum += __shfl_xor(wsum, 16); wsum += __shfl_xor(wsum, 32);
    if (grp == 0) {
        float inv = cnt > 0 ? 1.f / wsum : 0.f;
        float4 b_lo = *(const float4*)&b1[c*8];
        float4 b_hi = *(const float4*)&b1[c*8 + 4];
        float o[8];
        o[0] = acc[0]*inv + b_lo.x; o[1] = acc[1]*inv + b_lo.y;
        o[2] = acc[2]*inv + b_lo.z; o[3] = acc[3]*inv + b_lo.w;
        o[4] = acc[4]*inv + b_hi.x; o[5] = acc[5]*inv + b_hi.y;
        o[6] = acc[6]*inv + b_hi.z; o[7] = acc[7]*inv + b_hi.w;
        #pragma unroll
        for (int j = 0; j < 8; ++j) o[j] = o[j] > 0.f ? o[j] : __expf(o[j]) - 1.f;
        float* orow = &agg1[((size_t)(b*ND0 + d))*64 + c*8];
        *(float4*)&orow[0] = make_float4(o[0], o[1], o[2], o[3]);
        *(float4*)&orow[4] = make_float4(o[4], o[5], o[6], o[7]);
    }
}

// ---------------- layer 2 node transform (register-blocked GEMM) -----------
__global__ __launch_bounds__(256) void k5_node2(
        const float* __restrict__ h, const float* __restrict__ W2,
        const float* __restrict__ a_src2, const float* __restrict__ a_dst2,
        float* __restrict__ ht2, float* __restrict__ es2, float* __restrict__ ed2) {
    __shared__ float xt[64*132];
    __shared__ float Wl[64*32];
    __shared__ float as2[32], ad2[32];
    int t = threadIdx.x;
    for (int i = t; i < 512; i += 256)
        *(float4*)&Wl[i*4] = *(const float4*)&W2[i*4];
    if (t < 32) { as2[t] = a_src2[t]; ad2[t] = a_dst2[t]; }
    int rr = t & 127;
    int q  = t >> 7;
    int row_s = blockIdx.x * 128 + rr;
    bool valid = row_s < NB*ND0;
    const float* hrow = h + (size_t)row_s * 64;
    #pragma unroll
    for (int j = 0; j < 8; ++j) {
        int k = q * 32 + j * 4;
        float4 v = valid ? *(const float4*)&hrow[k] : make_float4(0.f,0.f,0.f,0.f);
        xt[(k+0)*132 + rr] = v.x;
        xt[(k+1)*132 + rr] = v.y;
        xt[(k+2)*132 + rr] = v.z;
        xt[(k+3)*132 + rr] = v.w;
    }
    __syncthreads();
    int c0 = (t & 7) * 4;
    int r0 = (t >> 3) * 4;
    float acc[4][4] = {};
    #pragma unroll 16
    for (int k = 0; k < 64; ++k) {
        float4 a = *(const float4*)&xt[k*132 + r0];
        float4 w = *(const float4*)&Wl[k*32 + c0];
        acc[0][0] = fmaf(a.x, w.x, acc[0][0]); acc[0][1] = fmaf(a.x, w.y, acc[0][1]);
        acc[0][2] = fmaf(a.x, w.z, acc[0][2]); acc[0][3] = fmaf(a.x, w.w, acc[0][3]);
        acc[1][0] = fmaf(a.y, w.x, acc[1][0]); acc[1][1] = fmaf(a.y, w.y, acc[1][1]);
        acc[1][2] = fmaf(a.y, w.z, acc[1][2]); acc[1][3] = fmaf(a.y, w.w, acc[1][3]);
        acc[2][0] = fmaf(a.z, w.x, acc[2][0]); acc[2][1] = fmaf(a.z, w.y, acc[2][1]);
        acc[2][2] = fmaf(a.z, w.z, acc[2][2]); acc[2][3] = fmaf(a.z, w.w, acc[2][3]);
        acc[3][0] = fmaf(a.w, w.x, acc[3][0]); acc[3][1] = fmaf(a.w, w.y, acc[3][1]);
        acc[3][2] = fmaf(a.w, w.z, acc[3][2]); acc[3][3] = fmaf(a.w, w.w, acc[3][3]);
    }
    float s0 = as2[c0], s1 = as2[c0+1], s2 = as2[c0+2], s3 = as2[c0+3];
    float d0 = ad2[c0], d1 = ad2[c0+1], d2 = ad2[c0+2], d3 = ad2[c0+3];
    #pragma unroll
    for (int i = 0; i < 4; ++i) {
        int row = blockIdx.x * 128 + r0 + i;
        float ps = acc[i][0]*s0 + acc[i][1]*s1 + acc[i][2]*s2 + acc[i][3]*s3;
        float pd = acc[i][0]*d0 + acc[i][1]*d1 + acc[i][2]*d2 + acc[i][3]*d3;
        ps += __shfl_xor(ps, 1); ps += __shfl_xor(ps, 2); ps += __shfl_xor(ps, 4);
        pd += __shfl_xor(pd, 1); pd += __shfl_xor(pd, 2); pd += __shfl_xor(pd, 4);
        if (row < NB*ND0) {
            *(float4*)&ht2[(size_t)row*32 + c0] =
                make_float4(acc[i][0], acc[i][1], acc[i][2], acc[i][3]);
            if ((t & 7) == 0) { es2[row] = ps; ed2[row] = pd; }
        }
    }
}

// ---------------- layer 2 per-dst aggregation (4-deep pipeline) ------------
__global__ __launch_bounds__(256) void k7_agg2(
        const int* __restrict__ srcsort1, const int* __restrict__ cur1,
        const int* __restrict__ res1,
        const float* __restrict__ es2, const float* __restrict__ ed2,
        const float* __restrict__ ht2, const float* __restrict__ b2,
        float* __restrict__ outp) {
    int b = blockIdx.x / (ND1/4);
    int chunk = blockIdx.x - b * (ND1/4);
    int d = chunk * 4 + (threadIdx.x >> 6);
    int lane = threadIdx.x & 63;
    int grp = lane >> 3;                   // edge slot 0..7
    int c = lane & 7;                      // channel quad: channels 4c..4c+3
    int dn = res1[d];
    float edv = ed2[b*ND0 + dn];
    int start = d * CAP;
    int cnt = cur1[d];
    const float* esb = es2 + (size_t)b*ND0;
    const float* htb = ht2 + (size_t)b*ND0*32;
    float ax = 0.f, ay = 0.f, az = 0.f, aw = 0.f, wsum = 0.f;
    int i = grp;
    bool v0 = i      < cnt, v1 = i + 8  < cnt,
         v2 = i + 16 < cnt, v3 = i + 24 < cnt;
    int s0 = v0 ? srcsort1[start + i]      : 0;
    int s1 = v1 ? srcsort1[start + i + 8]  : 0;
    int s2 = v2 ? srcsort1[start + i + 16] : 0;
    int s3 = v3 ? srcsort1[start + i + 24] : 0;
    for (;;) {
        float lg0 = esb[s0], lg1 = esb[s1], lg2 = esb[s2], lg3 = esb[s3];
        float4 h0 = *(const float4*)&htb[(size_t)s0*32 + c*4];
        float4 h1 = *(const float4*)&htb[(size_t)s1*32 + c*4];
        float4 h2 = *(const float4*)&htb[(size_t)s2*32 + c*4];
        float4 h3 = *(const float4*)&htb[(size_t)s3*32 + c*4];
        int ni = i + 32;
        bool nv0 = ni      < cnt, nv1 = ni + 8  < cnt,
             nv2 = ni + 16 < cnt, nv3 = ni + 24 < cnt;
        int t0 = nv0 ? srcsort1[start + ni]      : 0;
        int t1 = nv1 ? srcsort1[start + ni + 8]  : 0;
        int t2 = nv2 ? srcsort1[start + ni + 16] : 0;
        int t3 = nv3 ? srcsort1[start + ni + 24] : 0;
        lg0 += edv; lg1 += edv; lg2 += edv; lg3 += edv;
        lg0 = lg0 > 0.f ? lg0 : NEG * lg0;
        lg1 = lg1 > 0.f ? lg1 : NEG * lg1;
        lg2 = lg2 > 0.f ? lg2 : NEG * lg2;
        lg3 = lg3 > 0.f ? lg3 : NEG * lg3;
        float w0 = v0 ? __expf(lg0) : 0.f;
        float w1 = v1 ? __expf(lg1) : 0.f;
        float w2 = v2 ? __expf(lg2) : 0.f;
        float w3 = v3 ? __expf(lg3) : 0.f;
        ax = fmaf(w0, h0.x, ax); ay = fmaf(w0, h0.y, ay);
        az = fmaf(w0, h0.z, az); aw = fmaf(w0, h0.w, aw);
        ax = fmaf(w1, h1.x, ax); ay = fmaf(w1, h1.y, ay);
        az = fmaf(w1, h1.z, az); aw = fmaf(w1, h1.w, aw);
        ax = fmaf(w2, h2.x, ax); ay = fmaf(w2, h2.y, ay);
        az = fmaf(w2, h2.z, az); aw = fmaf(w2, h2.w, aw);
        ax = fmaf(w3, h3.x, ax); ay = fmaf(w3, h3.y, ay);
        az = fmaf(w3, h3.z, az); aw = fmaf(w3, h3.w, aw);
        wsum += (w0 + w1) + (w2 + w3);
        i = ni; s0 = t0; s1 = t1; s2 = t2; s3 = t3;
        v0 = nv0; v1 = nv1; v2 = nv2; v3 = nv3;
        if (i >= cnt) break;
    }
    ax += __shfl_xor(ax, 8); ax += __shfl_xor(ax, 16); ax += __shfl_xor(ax, 32);
    ay += __shfl_xor(ay, 8); ay += __shfl_xor(ay, 16); ay += __shfl_xor(ay, 32);
    az += __shfl_xor(az, 8); az += __shfl_xor(az, 16); az += __shfl_xor(az, 32);
    aw += __shfl_xor(aw, 8); aw += __shfl_xor(aw, 16); aw += __shfl_xor(aw, 32);
    wsum += __shfl_xor(wsum, 8); wsum += __shfl_xor(wsum, 16); wsum += __shfl_xor(wsum, 32);
    if (grp == 0) {
        float inv = cnt > 0 ? 1.f / wsum : 0.f;
        float4 bb = *(const float4*)&b2[c*4];
        float4 o;
        o.x = ax*inv + bb.x; o.y = ay*inv + bb.y;
        o.z = az*inv + bb.z; o.w = aw*inv + bb.w;
        *(float4*)&outp[((size_t)(b*ND1 + d))*32 + c*4] = o;
    }
}

extern "C" void kernel_launch(void* const* d_in, const int* in_sizes, int n_in,
                              void* d_out, int out_size, void* d_ws, size_t ws_size,
                              hipStream_t stream) {
    const float* x        = (const float*)d_in[0];
    const int*   n_id0    = (const int*)d_in[1];
    const int*   res0     = (const int*)d_in[2];
    const int*   esrc0    = (const int*)d_in[3];
    const int*   edst0    = (const int*)d_in[4];
    const int*   res1     = (const int*)d_in[5];
    const int*   esrc1    = (const int*)d_in[6];
    const int*   edst1    = (const int*)d_in[7];
    const float* W1       = (const float*)d_in[8];
    const float* a_src1   = (const float*)d_in[9];
    const float* a_dst1   = (const float*)d_in[10];
    const float* b1       = (const float*)d_in[11];
    const float* W2       = (const float*)d_in[12];
    const float* a_src2   = (const float*)d_in[13];
    const float* a_dst2   = (const float*)d_in[14];
    const float* b2       = (const float*)d_in[15];
    float* outp = (float*)d_out;

    char* base = (char*)d_ws;
    unsigned short* ht1b = (unsigned short*)base;            // 120000*64*2  = 15,360,000 B
    float* es1  = (float*)(base + 15360000);                 // 960,000 f
    float* ed1  = es1 + 960000;                              // 960,000 f
    float* agg1 = ed1 + 960000;                              // 3,840,000 f
    float* ht2  = agg1 + 3840000;                            // 1,920,000 f
    float* es2  = ht2 + 1920000;                             // 60,000 f
    float* ed2  = es2 + 60000;                               // 60,000 f
    // cur0|cur1 contiguous so one memsetAsync zeroes both
    int* cur0     = (int*)(ed2 + 60000);                     // 15000
    int* cur1     = cur0 + ND0;                              // 7500
    int* srcsort0 = cur1 + ND1;                              // 15000*64 = 960,000
    int* srcsort1 = srcsort0 + ND0*CAP;                      // 7500*64  = 480,000
    // total ~52.4 MB

    hipMemsetAsync(cur0, 0, (ND0 + ND1) * sizeof(int), stream);
    kA_gemm_scat<<<K1B + SB, 256, 0, stream>>>(x, n_id0, W1, a_src1, a_dst1,
                                               ht1b, es1, ed1,
                                               esrc0, edst0, esrc1, edst1,
                                               cur0, cur1, srcsort0, srcsort1);
    k3_agg1<<<NB*(ND0/4), 256, 0, stream>>>(srcsort0, cur0, res0, es1, ed1, ht1b, b1, agg1);
    k5_node2<<<(NB*ND0 + 127)/128, 256, 0, stream>>>(agg1, W2, a_src2, a_dst2, ht2, es2, ed2);
    k7_agg2<<<NB*(ND1/4), 256, 0, stream>>>(srcsort1, cur1, res1, es2, ed2, ht2, b2, outp);
}

// Round 2
// 207.304 us; speedup vs baseline: 1.2015x; 1.0117x over previous
//
#include <hip/hip_runtime.h>

#define NB 4
#define NT 40000
#define NS0 30000
#define ND0 15000
#define NE0 360000
#define ND1 7500
#define NE1 180000
#define NEG 0.2f

#define CAP 64                            // bucket capacity per dst (avg deg 24)
#define K1B ((NB*NS0)/64)                 // 1875 GEMM blocks
#define SB  ((NE0 + NE1 + 255)/256)       // 2110 scatter blocks

typedef __attribute__((ext_vector_type(8))) short bf8;
typedef __attribute__((ext_vector_type(4))) float f4;

__device__ __forceinline__ unsigned short f2bf(float f) {
    unsigned u = __float_as_uint(f);
    u += 0x7FFF + ((u >> 16) & 1);          // round-to-nearest-even
    return (unsigned short)(u >> 16);
}
// packed bf16 pair in a uint: low ushort = even channel, high = odd channel
__device__ __forceinline__ float bf_lo(unsigned u) { return __uint_as_float(u << 16); }
__device__ __forceinline__ float bf_hi(unsigned u) { return __uint_as_float(u & 0xFFFF0000u); }

// -------- fused: bucket scatter (CSR without scan) + layer-1 MFMA GEMM -----
// blocks [0, SB): edge scatter into fixed-capacity (CAP=64) per-dst buckets —
// latency/atomic-bound, launched FIRST so it issues while GEMM blocks fill in.
// blocks [SB, SB+K1B): node transform.
__global__ __launch_bounds__(256) void kA_gemm_scat(
        const float* __restrict__ x, const int* __restrict__ n_id0,
        const float* __restrict__ W1, const float* __restrict__ a_src,
        const float* __restrict__ a_dst,
        unsigned short* __restrict__ ht1b, float* __restrict__ es1, float* __restrict__ ed1,
        const int* __restrict__ esrc0, const int* __restrict__ edst0,
        const int* __restrict__ esrc1, const int* __restrict__ edst1,
        int* __restrict__ cur0, int* __restrict__ cur1,
        int* __restrict__ srcsort0, int* __restrict__ srcsort1) {
    __shared__ unsigned short xtb[64*72];
    __shared__ unsigned short wtb[64*72];
    __shared__ float asl[64], adl[64];
    if (blockIdx.x < SB) {                   // ---- scatter part ----
        int t = blockIdx.x * 256 + threadIdx.x;
        if (t < NE0) {
            int d = edst0[t];
            int pos = atomicAdd(&cur0[d], 1);
            if (pos < CAP) srcsort0[d*CAP + pos] = esrc0[t];
        } else if (t < NE0 + NE1) {
            int e = t - NE0;
            int d = edst1[e];
            int pos = atomicAdd(&cur1[d], 1);
            if (pos < CAP) srcsort1[d*CAP + pos] = esrc1[e];
        }
        return;
    }
    // ---- GEMM part ----
    int bid = blockIdx.x - SB;
    int t = threadIdx.x;
    {
        int k = t >> 2, nb = (t & 3) * 16;
        const float* wrow = &W1[k*64 + nb];
        #pragma unroll
        for (int j = 0; j < 16; j += 4) {
            float4 v = *(const float4*)&wrow[j];
            wtb[(nb+j+0)*72 + k] = f2bf(v.x);
            wtb[(nb+j+1)*72 + k] = f2bf(v.y);
            wtb[(nb+j+2)*72 + k] = f2bf(v.z);
            wtb[(nb+j+3)*72 + k] = f2bf(v.w);
        }
    }
    if (t < 64) { asl[t] = a_src[t]; adl[t] = a_dst[t]; }
    {
        int rr = t & 63;
        int q4 = t >> 6;
        int row_s = bid * 64 + rr;                  // < 120000 (1875*64)
        int bs = row_s / NS0;
        int ns = row_s - bs * NS0;
        const float* xrow = x + ((size_t)(bs * NT + n_id0[ns])) * 64;
        #pragma unroll
        for (int j = 0; j < 4; ++j) {
            int k = q4 * 16 + j * 4;
            float4 v = *(const float4*)&xrow[k];
            ushort4 u;
            u.x = f2bf(v.x); u.y = f2bf(v.y); u.z = f2bf(v.z); u.w = f2bf(v.w);
            *(ushort4*)&xtb[rr*72 + k] = u;
        }
    }
    __syncthreads();
    int w = t >> 6, lane = t & 63, quad = lane >> 4, cl = lane & 15;
    int arow = 16*w + cl;
    bf8 a0 = *(const bf8*)&xtb[arow*72 + quad*8];        // A[m=cl][k=quad*8+j]
    bf8 a1 = *(const bf8*)&xtb[arow*72 + 32 + quad*8];   // k+32
    f4 acc[4];
    #pragma unroll
    for (int sub = 0; sub < 4; ++sub) {
        int n = sub*16 + cl;
        bf8 b0 = *(const bf8*)&wtb[n*72 + quad*8];       // B[k][n=cl]
        bf8 b1 = *(const bf8*)&wtb[n*72 + 32 + quad*8];
        f4 c = {0.f, 0.f, 0.f, 0.f};
        c = __builtin_amdgcn_mfma_f32_16x16x32_bf16(a0, b0, c, 0, 0, 0);
        c = __builtin_amdgcn_mfma_f32_16x16x32_bf16(a1, b1, c, 0, 0, 0);
        acc[sub] = c;
    }
    int rbase = bid*64 + 16*w + quad*4;
    #pragma unroll
    for (int sub = 0; sub < 4; ++sub)
        #pragma unroll
        for (int r = 0; r < 4; ++r)
            ht1b[(size_t)(rbase + r)*64 + sub*16 + cl] = f2bf(acc[sub][r]);
    #pragma unroll
    for (int r = 0; r < 4; ++r) {
        #pragma unroll
        for (int sub = 0; sub < 4; ++sub) {
            int col = sub*16 + cl;
            float ps = acc[sub][r] * asl[col];
            float pd = acc[sub][r] * adl[col];
            ps += __shfl_xor(ps, 1); ps += __shfl_xor(ps, 2); ps += __shfl_xor(ps, 4);
            pd += __shfl_xor(pd, 1); pd += __shfl_xor(pd, 2); pd += __shfl_xor(pd, 4);
            if ((cl & 7) == 0) {
                int h = sub*2 + (cl >> 3);
                es1[(rbase + r)*8 + h] = ps;
                ed1[(rbase + r)*8 + h] = pd;
            }
        }
    }
}

// -------- fused: layer-1 per-dst aggregation + layer-2 node transform ------
// Main loop: 1 dst/wave, 8 x 8-lane edge slots, 4-deep branch-free pipeline.
// Epilogue: h(d) (64 ch) goes to LDS, then the wave does the 64x32 W2 matvec
// + att dots in-register — k5_node2 and the 30 MB agg1 round trip are gone.
__global__ __launch_bounds__(256) void k3_agg1_node2(
        const int* __restrict__ srcsort0, const int* __restrict__ cur0,
        const int* __restrict__ res0,
        const float* __restrict__ es1, const float* __restrict__ ed1,
        const unsigned short* __restrict__ ht1b, const float* __restrict__ b1,
        const float* __restrict__ W2, const float* __restrict__ a_src2,
        const float* __restrict__ a_dst2,
        float* __restrict__ ht2, float* __restrict__ es2, float* __restrict__ ed2) {
    __shared__ float W2l[64*32];           // 8 KB, L1-hot across blocks
    __shared__ float as2[32], ad2[32];
    __shared__ float hsh[4][64];           // per-wave h(d)
    int t = threadIdx.x;
    for (int i = t; i < 512; i += 256)
        *(float4*)&W2l[i*4] = *(const float4*)&W2[i*4];
    if (t < 32) { as2[t] = a_src2[t]; ad2[t] = a_dst2[t]; }
    int b = blockIdx.x / (ND0/4);
    int chunk = blockIdx.x - b * (ND0/4);
    int wv = t >> 6;
    int d = chunk * 4 + wv;
    int lane = t & 63;
    int grp = lane >> 3;                   // edge slot 0..7
    int c = lane & 7;                      // head index; channels 8c..8c+7
    int dn = res0[d];
    float edv = ed1[(b*NS0 + dn)*8 + c];
    int start = d * CAP;
    int cnt = cur0[d];
    const float* esb = es1 + (size_t)b*NS0*8;
    const unsigned short* htb = ht1b + (size_t)b*NS0*64;
    float acc[8] = {};
    float wsum = 0.f;
    int i = grp;
    bool v0 = i      < cnt, v1 = i + 8  < cnt,
         v2 = i + 16 < cnt, v3 = i + 24 < cnt;
    int s0 = v0 ? srcsort0[start + i]      : 0;
    int s1 = v1 ? srcsort0[start + i + 8]  : 0;
    int s2 = v2 ? srcsort0[start + i + 16] : 0;
    int s3 = v3 ? srcsort0[start + i + 24] : 0;
    for (;;) {
        float e0 = esb[s0*8 + c], e1 = esb[s1*8 + c];
        float e2 = esb[s2*8 + c], e3 = esb[s3*8 + c];
        uint4 h0 = *(const uint4*)&htb[(size_t)s0*64 + c*8];
        uint4 h1 = *(const uint4*)&htb[(size_t)s1*64 + c*8];
        uint4 h2 = *(const uint4*)&htb[(size_t)s2*64 + c*8];
        uint4 h3 = *(const uint4*)&htb[(size_t)s3*64 + c*8];
        int ni = i + 32;
        bool nv0 = ni      < cnt, nv1 = ni + 8  < cnt,
             nv2 = ni + 16 < cnt, nv3 = ni + 24 < cnt;
        int t0 = nv0 ? srcsort0[start + ni]      : 0;
        int t1 = nv1 ? srcsort0[start + ni + 8]  : 0;
        int t2 = nv2 ? srcsort0[start + ni + 16] : 0;
        int t3 = nv3 ? srcsort0[start + ni + 24] : 0;
        e0 += edv; e1 += edv; e2 += edv; e3 += edv;
        e0 = e0 > 0.f ? e0 : NEG * e0;
        e1 = e1 > 0.f ? e1 : NEG * e1;
        e2 = e2 > 0.f ? e2 : NEG * e2;
        e3 = e3 > 0.f ? e3 : NEG * e3;
        float w0 = v0 ? __expf(e0) : 0.f;
        float w1 = v1 ? __expf(e1) : 0.f;
        float w2 = v2 ? __expf(e2) : 0.f;
        float w3 = v3 ? __expf(e3) : 0.f;
        acc[0] = fmaf(w0, bf_lo(h0.x), acc[0]); acc[1] = fmaf(w0, bf_hi(h0.x), acc[1]);
        acc[2] = fmaf(w0, bf_lo(h0.y), acc[2]); acc[3] = fmaf(w0, bf_hi(h0.y), acc[3]);
        acc[4] = fmaf(w0, bf_lo(h0.z), acc[4]); acc[5] = fmaf(w0, bf_hi(h0.z), acc[5]);
        acc[6] = fmaf(w0, bf_lo(h0.w), acc[6]); acc[7] = fmaf(w0, bf_hi(h0.w), acc[7]);
        acc[0] = fmaf(w1, bf_lo(h1.x), acc[0]); acc[1] = fmaf(w1, bf_hi(h1.x), acc[1]);
        acc[2] = fmaf(w1, bf_lo(h1.y), acc[2]); acc[3] = fmaf(w1, bf_hi(h1.y), acc[3]);
        acc[4] = fmaf(w1, bf_lo(h1.z), acc[4]); acc[5] = fmaf(w1, bf_hi(h1.z), acc[5]);
        acc[6] = fmaf(w1, bf_lo(h1.w), acc[6]); acc[7] = fmaf(w1, bf_hi(h1.w), acc[7]);
        acc[0] = fmaf(w2, bf_lo(h2.x), acc[0]); acc[1] = fmaf(w2, bf_hi(h2.x), acc[1]);
        acc[2] = fmaf(w2, bf_lo(h2.y), acc[2]); acc[3] = fmaf(w2, bf_hi(h2.y), acc[3]);
        acc[4] = fmaf(w2, bf_lo(h2.z), acc[4]); acc[5] = fmaf(w2, bf_hi(h2.z), acc[5]);
        acc[6] = fmaf(w2, bf_lo(h2.w), acc[6]); acc[7] = fmaf(w2, bf_hi(h2.w), acc[7]);
        acc[0] = fmaf(w3, bf_lo(h3.x), acc[0]); acc[1] = fmaf(w3, bf_hi(h3.x), acc[1]);
        acc[2] = fmaf(w3, bf_lo(h3.y), acc[2]); acc[3] = fmaf(w3, bf_hi(h3.y), acc[3]);
        acc[4] = fmaf(w3, bf_lo(h3.z), acc[4]); acc[5] = fmaf(w3, bf_hi(h3.z), acc[5]);
        acc[6] = fmaf(w3, bf_lo(h3.w), acc[6]); acc[7] = fmaf(w3, bf_hi(h3.w), acc[7]);
        wsum += (w0 + w1) + (w2 + w3);
        i = ni; s0 = t0; s1 = t1; s2 = t2; s3 = t3;
        v0 = nv0; v1 = nv1; v2 = nv2; v3 = nv3;
        if (i >= cnt) break;
    }
    #pragma unroll
    for (int j = 0; j < 8; ++j) {
        acc[j] += __shfl_xor(acc[j], 8);
        acc[j] += __shfl_xor(acc[j], 16);
        acc[j] += __shfl_xor(acc[j], 32);
    }
    wsum += __shfl_xor(wsum, 8); wsum += __shfl_xor(wsum, 16); wsum += __shfl_xor(wsum, 32);
    if (grp == 0) {
        float inv = cnt > 0 ? 1.f / wsum : 0.f;
        float4 b_lo = *(const float4*)&b1[c*8];
        float4 b_hi = *(const float4*)&b1[c*8 + 4];
        float o[8];
        o[0] = acc[0]*inv + b_lo.x; o[1] = acc[1]*inv + b_lo.y;
        o[2] = acc[2]*inv + b_lo.z; o[3] = acc[3]*inv + b_lo.w;
        o[4] = acc[4]*inv + b_hi.x; o[5] = acc[5]*inv + b_hi.y;
        o[6] = acc[6]*inv + b_hi.z; o[7] = acc[7]*inv + b_hi.w;
        #pragma unroll
        for (int j = 0; j < 8; ++j) o[j] = o[j] > 0.f ? o[j] : __expf(o[j]) - 1.f;
        float* hrow = &hsh[wv][c*8];
        *(float4*)&hrow[0] = make_float4(o[0], o[1], o[2], o[3]);
        *(float4*)&hrow[4] = make_float4(o[4], o[5], o[6], o[7]);
    }
    __syncthreads();
    // ---- layer-2 node transform: out[c2] = sum_k h[k] * W2[k][c2] ----
    int c2 = lane & 31, half = lane >> 5;
    float acc2 = 0.f;
    #pragma unroll
    for (int k = 0; k < 32; ++k)
        acc2 = fmaf(hsh[wv][half*32 + k], W2l[(half*32 + k)*32 + c2], acc2);
    acc2 += __shfl_xor(acc2, 32);          // lanes 0..31 (and 32..63) hold out[c2]
    float ps = acc2 * as2[c2];
    float pd = acc2 * ad2[c2];
    ps += __shfl_xor(ps, 1); ps += __shfl_xor(ps, 2); ps += __shfl_xor(ps, 4);
    ps += __shfl_xor(ps, 8); ps += __shfl_xor(ps, 16);
    pd += __shfl_xor(pd, 1); pd += __shfl_xor(pd, 2); pd += __shfl_xor(pd, 4);
    pd += __shfl_xor(pd, 8); pd += __shfl_xor(pd, 16);
    int row = b*ND0 + d;
    if (half == 0) ht2[(size_t)row*32 + c2] = acc2;   // coalesced 128 B
    if (lane == 0) { es2[row] = ps; ed2[row] = pd; }
}

// ---------------- layer 2 per-dst aggregation (4-deep pipeline) ------------
__global__ __launch_bounds__(256) void k7_agg2(
        const int* __restrict__ srcsort1, const int* __restrict__ cur1,
        const int* __restrict__ res1,
        const float* __restrict__ es2, const float* __restrict__ ed2,
        const float* __restrict__ ht2, const float* __restrict__ b2,
        float* __restrict__ outp) {
    int b = blockIdx.x / (ND1/4);
    int chunk = blockIdx.x - b * (ND1/4);
    int d = chunk * 4 + (threadIdx.x >> 6);
    int lane = threadIdx.x & 63;
    int grp = lane >> 3;                   // edge slot 0..7
    int c = lane & 7;                      // channel quad: channels 4c..4c+3
    int dn = res1[d];
    float edv = ed2[b*ND0 + dn];
    int start = d * CAP;
    int cnt = cur1[d];
    const float* esb = es2 + (size_t)b*ND0;
    const float* htb = ht2 + (size_t)b*ND0*32;
    float ax = 0.f, ay = 0.f, az = 0.f, aw = 0.f, wsum = 0.f;
    int i = grp;
    bool v0 = i      < cnt, v1 = i + 8  < cnt,
         v2 = i + 16 < cnt, v3 = i + 24 < cnt;
    int s0 = v0 ? srcsort1[start + i]      : 0;
    int s1 = v1 ? srcsort1[start + i + 8]  : 0;
    int s2 = v2 ? srcsort1[start + i + 16] : 0;
    int s3 = v3 ? srcsort1[start + i + 24] : 0;
    for (;;) {
        float lg0 = esb[s0], lg1 = esb[s1], lg2 = esb[s2], lg3 = esb[s3];
        float4 h0 = *(const float4*)&htb[(size_t)s0*32 + c*4];
        float4 h1 = *(const float4*)&htb[(size_t)s1*32 + c*4];
        float4 h2 = *(const float4*)&htb[(size_t)s2*32 + c*4];
        float4 h3 = *(const float4*)&htb[(size_t)s3*32 + c*4];
        int ni = i + 32;
        bool nv0 = ni      < cnt, nv1 = ni + 8  < cnt,
             nv2 = ni + 16 < cnt, nv3 = ni + 24 < cnt;
        int t0 = nv0 ? srcsort1[start + ni]      : 0;
        int t1 = nv1 ? srcsort1[start + ni + 8]  : 0;
        int t2 = nv2 ? srcsort1[start + ni + 16] : 0;
        int t3 = nv3 ? srcsort1[start + ni + 24] : 0;
        lg0 += edv; lg1 += edv; lg2 += edv; lg3 += edv;
        lg0 = lg0 > 0.f ? lg0 : NEG * lg0;
        lg1 = lg1 > 0.f ? lg1 : NEG * lg1;
        lg2 = lg2 > 0.f ? lg2 : NEG * lg2;
        lg3 = lg3 > 0.f ? lg3 : NEG * lg3;
        float w0 = v0 ? __expf(lg0) : 0.f;
        float w1 = v1 ? __expf(lg1) : 0.f;
        float w2 = v2 ? __expf(lg2) : 0.f;
        float w3 = v3 ? __expf(lg3) : 0.f;
        ax = fmaf(w0, h0.x, ax); ay = fmaf(w0, h0.y, ay);
        az = fmaf(w0, h0.z, az); aw = fmaf(w0, h0.w, aw);
        ax = fmaf(w1, h1.x, ax); ay = fmaf(w1, h1.y, ay);
        az = fmaf(w1, h1.z, az); aw = fmaf(w1, h1.w, aw);
        ax = fmaf(w2, h2.x, ax); ay = fmaf(w2, h2.y, ay);
        az = fmaf(w2, h2.z, az); aw = fmaf(w2, h2.w, aw);
        ax = fmaf(w3, h3.x, ax); ay = fmaf(w3, h3.y, ay);
        az = fmaf(w3, h3.z, az); aw = fmaf(w3, h3.w, aw);
        wsum += (w0 + w1) + (w2 + w3);
        i = ni; s0 = t0; s1 = t1; s2 = t2; s3 = t3;
        v0 = nv0; v1 = nv1; v2 = nv2; v3 = nv3;
        if (i >= cnt) break;
    }
    ax += __shfl_xor(ax, 8); ax += __shfl_xor(ax, 16); ax += __shfl_xor(ax, 32);
    ay += __shfl_xor(ay, 8); ay += __shfl_xor(ay, 16); ay += __shfl_xor(ay, 32);
    az += __shfl_xor(az, 8); az += __shfl_xor(az, 16); az += __shfl_xor(az, 32);
    aw += __shfl_xor(aw, 8); aw += __shfl_xor(aw, 16); aw += __shfl_xor(aw, 32);
    wsum += __shfl_xor(wsum, 8); wsum += __shfl_xor(wsum, 16); wsum += __shfl_xor(wsum, 32);
    if (grp == 0) {
        float inv = cnt > 0 ? 1.f / wsum : 0.f;
        float4 bb = *(const float4*)&b2[c*4];
        float4 o;
        o.x = ax*inv + bb.x; o.y = ay*inv + bb.y;
        o.z = az*inv + bb.z; o.w = aw*inv + bb.w;
        *(float4*)&outp[((size_t)(b*ND1 + d))*32 + c*4] = o;
    }
}

extern "C" void kernel_launch(void* const* d_in, const int* in_sizes, int n_in,
                              void* d_out, int out_size, void* d_ws, size_t ws_size,
                              hipStream_t stream) {
    const float* x        = (const float*)d_in[0];
    const int*   n_id0    = (const int*)d_in[1];
    const int*   res0     = (const int*)d_in[2];
    const int*   esrc0    = (const int*)d_in[3];
    const int*   edst0    = (const int*)d_in[4];
    const int*   res1     = (const int*)d_in[5];
    const int*   esrc1    = (const int*)d_in[6];
    const int*   edst1    = (const int*)d_in[7];
    const float* W1       = (const float*)d_in[8];
    const float* a_src1   = (const float*)d_in[9];
    const float* a_dst1   = (const float*)d_in[10];
    const float* b1       = (const float*)d_in[11];
    const float* W2       = (const float*)d_in[12];
    const float* a_src2   = (const float*)d_in[13];
    const float* a_dst2   = (const float*)d_in[14];
    const float* b2       = (const float*)d_in[15];
    float* outp = (float*)d_out;

    char* base = (char*)d_ws;
    unsigned short* ht1b = (unsigned short*)base;            // 120000*64*2  = 15,360,000 B
    float* es1  = (float*)(base + 15360000);                 // 960,000 f
    float* ed1  = es1 + 960000;                              // 960,000 f
    float* ht2  = ed1 + 960000;                              // 1,920,000 f
    float* es2  = ht2 + 1920000;                             // 60,000 f
    float* ed2  = es2 + 60000;                               // 60,000 f
    // cur0|cur1 contiguous so one memsetAsync zeroes both
    int* cur0     = (int*)(ed2 + 60000);                     // 15000
    int* cur1     = cur0 + ND0;                              // 7500
    int* srcsort0 = cur1 + ND1;                              // 15000*64 = 960,000
    int* srcsort1 = srcsort0 + ND0*CAP;                      // 7500*64  = 480,000
    // total ~37 MB

    hipMemsetAsync(cur0, 0, (ND0 + ND1) * sizeof(int), stream);
    kA_gemm_scat<<<K1B + SB, 256, 0, stream>>>(x, n_id0, W1, a_src1, a_dst1,
                                               ht1b, es1, ed1,
                                               esrc0, edst0, esrc1, edst1,
                                               cur0, cur1, srcsort0, srcsort1);
    k3_agg1_node2<<<NB*(ND0/4), 256, 0, stream>>>(srcsort0, cur0, res0, es1, ed1, ht1b, b1,
                                                  W2, a_src2, a_dst2, ht2, es2, ed2);
    k7_agg2<<<NB*(ND1/4), 256, 0, stream>>>(srcsort1, cur1, res1, es2, ed2, ht2, b2, outp);
}

// Round 3
// 204.209 us; speedup vs baseline: 1.2197x; 1.0152x over previous
//
#include <hip/hip_runtime.h>

#define NB 4
#define NT 40000
#define NS0 30000
#define ND0 15000
#define NE0 360000
#define ND1 7500
#define NE1 180000
#define NEG 0.2f

#define CAP 64                            // bucket capacity per dst (avg deg 24)
#define K1B ((NB*NS0)/64)                 // 1875 GEMM blocks
#define SB4 ((NE0 + NE1 + 1023)/1024)     // 528 scatter blocks (4 edges/thread)

typedef __attribute__((ext_vector_type(8))) short bf8;
typedef __attribute__((ext_vector_type(4))) float f4;

__device__ __forceinline__ unsigned short f2bf(float f) {
    unsigned u = __float_as_uint(f);
    u += 0x7FFF + ((u >> 16) & 1);          // round-to-nearest-even
    return (unsigned short)(u >> 16);
}
// packed bf16 pair in a uint: low ushort = even channel, high = odd channel
__device__ __forceinline__ float bf_lo(unsigned u) { return __uint_as_float(u << 16); }
__device__ __forceinline__ float bf_hi(unsigned u) { return __uint_as_float(u & 0xFFFF0000u); }

// -------- fused: bucket scatter (CSR without scan) + layer-1 MFMA GEMM -----
// blocks [0, SB4): edge scatter, 4 edges/thread (ILP for atomic latency);
// blocks [SB4, SB4+K1B): node transform.
__global__ __launch_bounds__(256) void kA_gemm_scat(
        const float* __restrict__ x, const int* __restrict__ n_id0,
        const float* __restrict__ W1, const float* __restrict__ a_src,
        const float* __restrict__ a_dst,
        unsigned short* __restrict__ ht1b, float* __restrict__ es1, float* __restrict__ ed1,
        const int* __restrict__ esrc0, const int* __restrict__ edst0,
        const int* __restrict__ esrc1, const int* __restrict__ edst1,
        int* __restrict__ cur0, int* __restrict__ cur1,
        int* __restrict__ srcsort0, int* __restrict__ srcsort1) {
    __shared__ unsigned short xtb[64*72];
    __shared__ unsigned short wtb[64*72];
    __shared__ float asl[64], adl[64];
    if (blockIdx.x < SB4) {                  // ---- scatter part ----
        int base = blockIdx.x * 1024 + threadIdx.x;
        #pragma unroll
        for (int p = 0; p < 4; ++p) {
            int t = base + p * 256;
            if (t < NE0) {
                int d = edst0[t];
                int pos = atomicAdd(&cur0[d], 1);
                if (pos < CAP) srcsort0[d*CAP + pos] = esrc0[t];
            } else if (t < NE0 + NE1) {
                int e = t - NE0;
                int d = edst1[e];
                int pos = atomicAdd(&cur1[d], 1);
                if (pos < CAP) srcsort1[d*CAP + pos] = esrc1[e];
            }
        }
        return;
    }
    // ---- GEMM part ----
    int bid = blockIdx.x - SB4;
    int t = threadIdx.x;
    {
        int k = t >> 2, nb = (t & 3) * 16;
        const float* wrow = &W1[k*64 + nb];
        #pragma unroll
        for (int j = 0; j < 16; j += 4) {
            float4 v = *(const float4*)&wrow[j];
            wtb[(nb+j+0)*72 + k] = f2bf(v.x);
            wtb[(nb+j+1)*72 + k] = f2bf(v.y);
            wtb[(nb+j+2)*72 + k] = f2bf(v.z);
            wtb[(nb+j+3)*72 + k] = f2bf(v.w);
        }
    }
    if (t < 64) { asl[t] = a_src[t]; adl[t] = a_dst[t]; }
    {
        int rr = t & 63;
        int q4 = t >> 6;
        int row_s = bid * 64 + rr;                  // < 120000 (1875*64)
        int bs = row_s / NS0;
        int ns = row_s - bs * NS0;
        const float* xrow = x + ((size_t)(bs * NT + n_id0[ns])) * 64;
        #pragma unroll
        for (int j = 0; j < 4; ++j) {
            int k = q4 * 16 + j * 4;
            float4 v = *(const float4*)&xrow[k];
            ushort4 u;
            u.x = f2bf(v.x); u.y = f2bf(v.y); u.z = f2bf(v.z); u.w = f2bf(v.w);
            *(ushort4*)&xtb[rr*72 + k] = u;
        }
    }
    __syncthreads();
    int w = t >> 6, lane = t & 63, quad = lane >> 4, cl = lane & 15;
    int arow = 16*w + cl;
    bf8 a0 = *(const bf8*)&xtb[arow*72 + quad*8];        // A[m=cl][k=quad*8+j]
    bf8 a1 = *(const bf8*)&xtb[arow*72 + 32 + quad*8];   // k+32
    f4 acc[4];
    #pragma unroll
    for (int sub = 0; sub < 4; ++sub) {
        int n = sub*16 + cl;
        bf8 b0 = *(const bf8*)&wtb[n*72 + quad*8];       // B[k][n=cl]
        bf8 b1 = *(const bf8*)&wtb[n*72 + 32 + quad*8];
        f4 c = {0.f, 0.f, 0.f, 0.f};
        c = __builtin_amdgcn_mfma_f32_16x16x32_bf16(a0, b0, c, 0, 0, 0);
        c = __builtin_amdgcn_mfma_f32_16x16x32_bf16(a1, b1, c, 0, 0, 0);
        acc[sub] = c;
    }
    int rbase = bid*64 + 16*w + quad*4;
    #pragma unroll
    for (int sub = 0; sub < 4; ++sub)
        #pragma unroll
        for (int r = 0; r < 4; ++r)
            ht1b[(size_t)(rbase + r)*64 + sub*16 + cl] = f2bf(acc[sub][r]);
    #pragma unroll
    for (int r = 0; r < 4; ++r) {
        #pragma unroll
        for (int sub = 0; sub < 4; ++sub) {
            int col = sub*16 + cl;
            float ps = acc[sub][r] * asl[col];
            float pd = acc[sub][r] * adl[col];
            ps += __shfl_xor(ps, 1); ps += __shfl_xor(ps, 2); ps += __shfl_xor(ps, 4);
            pd += __shfl_xor(pd, 1); pd += __shfl_xor(pd, 2); pd += __shfl_xor(pd, 4);
            if ((cl & 7) == 0) {
                int h = sub*2 + (cl >> 3);
                es1[(rbase + r)*8 + h] = ps;
                ed1[(rbase + r)*8 + h] = pd;
            }
        }
    }
}

// -------- fused: layer-1 per-dst aggregation + layer-2 node transform ------
// XCD-pair batch pinning: xcd = blockIdx%8 (HW round-robin); batch b = xcd/2,
// so each XCD-pair's L2 (8 MiB) holds exactly one batch's gather working set
// (ht1b slice 3.84 MB + es1 slice 0.96 MB) -> L2-resident gathers.
// Single barrier at top (W2l staging); hsh handoff is same-wave LDS.
__global__ __launch_bounds__(256) void k3_agg1_node2(
        const int* __restrict__ srcsort0, const int* __restrict__ cur0,
        const int* __restrict__ res0,
        const float* __restrict__ es1, const float* __restrict__ ed1,
        const unsigned short* __restrict__ ht1b, const float* __restrict__ b1,
        const float* __restrict__ W2, const float* __restrict__ a_src2,
        const float* __restrict__ a_dst2,
        float* __restrict__ ht2, float* __restrict__ es2, float* __restrict__ ed2) {
    __shared__ float W2l[64*32];           // 8 KB, L1-hot across blocks
    __shared__ float as2[32], ad2[32];
    __shared__ float hsh[4][64];           // per-wave h(d)
    int t = threadIdx.x;
    for (int i = t; i < 512; i += 256)
        *(float4*)&W2l[i*4] = *(const float4*)&W2[i*4];
    if (t < 32) { as2[t] = a_src2[t]; ad2[t] = a_dst2[t]; }
    __syncthreads();                       // only barrier: W2l/as2/ad2 ready
    int xcd = blockIdx.x & 7;
    int b = xcd >> 1;                      // batch pinned to XCD pair
    int chunk = (blockIdx.x >> 3) * 2 + (xcd & 1);   // 0..3749 (bijective)
    int wv = t >> 6;
    int d = chunk * 4 + wv;
    int lane = t & 63;
    int grp = lane >> 3;                   // edge slot 0..7
    int c = lane & 7;                      // head index; channels 8c..8c+7
    int dn = res0[d];
    float edv = ed1[(b*NS0 + dn)*8 + c];
    int start = d * CAP;
    int cnt = cur0[d];
    const float* esb = es1 + (size_t)b*NS0*8;
    const unsigned short* htb = ht1b + (size_t)b*NS0*64;
    float acc[8] = {};
    float wsum = 0.f;
    int i = grp;
    bool v0 = i      < cnt, v1 = i + 8  < cnt,
         v2 = i + 16 < cnt, v3 = i + 24 < cnt;
    int s0 = v0 ? srcsort0[start + i]      : 0;
    int s1 = v1 ? srcsort0[start + i + 8]  : 0;
    int s2 = v2 ? srcsort0[start + i + 16] : 0;
    int s3 = v3 ? srcsort0[start + i + 24] : 0;
    for (;;) {
        float e0 = esb[s0*8 + c], e1 = esb[s1*8 + c];
        float e2 = esb[s2*8 + c], e3 = esb[s3*8 + c];
        uint4 h0 = *(const uint4*)&htb[(size_t)s0*64 + c*8];
        uint4 h1 = *(const uint4*)&htb[(size_t)s1*64 + c*8];
        uint4 h2 = *(const uint4*)&htb[(size_t)s2*64 + c*8];
        uint4 h3 = *(const uint4*)&htb[(size_t)s3*64 + c*8];
        int ni = i + 32;
        bool nv0 = ni      < cnt, nv1 = ni + 8  < cnt,
             nv2 = ni + 16 < cnt, nv3 = ni + 24 < cnt;
        int t0 = nv0 ? srcsort0[start + ni]      : 0;
        int t1 = nv1 ? srcsort0[start + ni + 8]  : 0;
        int t2 = nv2 ? srcsort0[start + ni + 16] : 0;
        int t3 = nv3 ? srcsort0[start + ni + 24] : 0;
        e0 += edv; e1 += edv; e2 += edv; e3 += edv;
        e0 = e0 > 0.f ? e0 : NEG * e0;
        e1 = e1 > 0.f ? e1 : NEG * e1;
        e2 = e2 > 0.f ? e2 : NEG * e2;
        e3 = e3 > 0.f ? e3 : NEG * e3;
        float w0 = v0 ? __expf(e0) : 0.f;
        float w1 = v1 ? __expf(e1) : 0.f;
        float w2 = v2 ? __expf(e2) : 0.f;
        float w3 = v3 ? __expf(e3) : 0.f;
        acc[0] = fmaf(w0, bf_lo(h0.x), acc[0]); acc[1] = fmaf(w0, bf_hi(h0.x), acc[1]);
        acc[2] = fmaf(w0, bf_lo(h0.y), acc[2]); acc[3] = fmaf(w0, bf_hi(h0.y), acc[3]);
        acc[4] = fmaf(w0, bf_lo(h0.z), acc[4]); acc[5] = fmaf(w0, bf_hi(h0.z), acc[5]);
        acc[6] = fmaf(w0, bf_lo(h0.w), acc[6]); acc[7] = fmaf(w0, bf_hi(h0.w), acc[7]);
        acc[0] = fmaf(w1, bf_lo(h1.x), acc[0]); acc[1] = fmaf(w1, bf_hi(h1.x), acc[1]);
        acc[2] = fmaf(w1, bf_lo(h1.y), acc[2]); acc[3] = fmaf(w1, bf_hi(h1.y), acc[3]);
        acc[4] = fmaf(w1, bf_lo(h1.z), acc[4]); acc[5] = fmaf(w1, bf_hi(h1.z), acc[5]);
        acc[6] = fmaf(w1, bf_lo(h1.w), acc[6]); acc[7] = fmaf(w1, bf_hi(h1.w), acc[7]);
        acc[0] = fmaf(w2, bf_lo(h2.x), acc[0]); acc[1] = fmaf(w2, bf_hi(h2.x), acc[1]);
        acc[2] = fmaf(w2, bf_lo(h2.y), acc[2]); acc[3] = fmaf(w2, bf_hi(h2.y), acc[3]);
        acc[4] = fmaf(w2, bf_lo(h2.z), acc[4]); acc[5] = fmaf(w2, bf_hi(h2.z), acc[5]);
        acc[6] = fmaf(w2, bf_lo(h2.w), acc[6]); acc[7] = fmaf(w2, bf_hi(h2.w), acc[7]);
        acc[0] = fmaf(w3, bf_lo(h3.x), acc[0]); acc[1] = fmaf(w3, bf_hi(h3.x), acc[1]);
        acc[2] = fmaf(w3, bf_lo(h3.y), acc[2]); acc[3] = fmaf(w3, bf_hi(h3.y), acc[3]);
        acc[4] = fmaf(w3, bf_lo(h3.z), acc[4]); acc[5] = fmaf(w3, bf_hi(h3.z), acc[5]);
        acc[6] = fmaf(w3, bf_lo(h3.w), acc[6]); acc[7] = fmaf(w3, bf_hi(h3.w), acc[7]);
        wsum += (w0 + w1) + (w2 + w3);
        i = ni; s0 = t0; s1 = t1; s2 = t2; s3 = t3;
        v0 = nv0; v1 = nv1; v2 = nv2; v3 = nv3;
        if (i >= cnt) break;
    }
    #pragma unroll
    for (int j = 0; j < 8; ++j) {
        acc[j] += __shfl_xor(acc[j], 8);
        acc[j] += __shfl_xor(acc[j], 16);
        acc[j] += __shfl_xor(acc[j], 32);
    }
    wsum += __shfl_xor(wsum, 8); wsum += __shfl_xor(wsum, 16); wsum += __shfl_xor(wsum, 32);
    if (grp == 0) {
        float inv = cnt > 0 ? 1.f / wsum : 0.f;
        float4 b_lo = *(const float4*)&b1[c*8];
        float4 b_hi = *(const float4*)&b1[c*8 + 4];
        float o[8];
        o[0] = acc[0]*inv + b_lo.x; o[1] = acc[1]*inv + b_lo.y;
        o[2] = acc[2]*inv + b_lo.z; o[3] = acc[3]*inv + b_lo.w;
        o[4] = acc[4]*inv + b_hi.x; o[5] = acc[5]*inv + b_hi.y;
        o[6] = acc[6]*inv + b_hi.z; o[7] = acc[7]*inv + b_hi.w;
        #pragma unroll
        for (int j = 0; j < 8; ++j) o[j] = o[j] > 0.f ? o[j] : __expf(o[j]) - 1.f;
        float* hrow = &hsh[wv][c*8];
        *(float4*)&hrow[0] = make_float4(o[0], o[1], o[2], o[3]);
        *(float4*)&hrow[4] = make_float4(o[4], o[5], o[6], o[7]);
    }
    // hsh[wv] written and read by the SAME wave -> lgkmcnt ordering suffices,
    // no __syncthreads (waves finish independently).
    // ---- layer-2 node transform: out[c2] = sum_k h[k] * W2[k][c2] ----
    int c2 = lane & 31, half = lane >> 5;
    float acc2 = 0.f;
    #pragma unroll
    for (int k = 0; k < 32; ++k)
        acc2 = fmaf(hsh[wv][half*32 + k], W2l[(half*32 + k)*32 + c2], acc2);
    acc2 += __shfl_xor(acc2, 32);          // lanes 0..31 (and 32..63) hold out[c2]
    float ps = acc2 * as2[c2];
    float pd = acc2 * ad2[c2];
    ps += __shfl_xor(ps, 1); ps += __shfl_xor(ps, 2); ps += __shfl_xor(ps, 4);
    ps += __shfl_xor(ps, 8); ps += __shfl_xor(ps, 16);
    pd += __shfl_xor(pd, 1); pd += __shfl_xor(pd, 2); pd += __shfl_xor(pd, 4);
    pd += __shfl_xor(pd, 8); pd += __shfl_xor(pd, 16);
    int row = b*ND0 + d;
    if (half == 0) ht2[(size_t)row*32 + c2] = acc2;   // coalesced 128 B
    if (lane == 0) { es2[row] = ps; ed2[row] = pd; }
}

// ---------------- layer 2 per-dst aggregation (4-deep pipeline) ------------
// Same XCD-pair batch pinning; grid padded to 7504 with chunk guard (7500%8!=0).
__global__ __launch_bounds__(256) void k7_agg2(
        const int* __restrict__ srcsort1, const int* __restrict__ cur1,
        const int* __restrict__ res1,
        const float* __restrict__ es2, const float* __restrict__ ed2,
        const float* __restrict__ ht2, const float* __restrict__ b2,
        float* __restrict__ outp) {
    int xcd = blockIdx.x & 7;
    int b = xcd >> 1;
    int chunk = (blockIdx.x >> 3) * 2 + (xcd & 1);
    if (chunk >= ND1/4) return;            // pad blocks (grid 7504)
    int d = chunk * 4 + (threadIdx.x >> 6);
    int lane = threadIdx.x & 63;
    int grp = lane >> 3;                   // edge slot 0..7
    int c = lane & 7;                      // channel quad: channels 4c..4c+3
    int dn = res1[d];
    float edv = ed2[b*ND0 + dn];
    int start = d * CAP;
    int cnt = cur1[d];
    const float* esb = es2 + (size_t)b*ND0;
    const float* htb = ht2 + (size_t)b*ND0*32;
    float ax = 0.f, ay = 0.f, az = 0.f, aw = 0.f, wsum = 0.f;
    int i = grp;
    bool v0 = i      < cnt, v1 = i + 8  < cnt,
         v2 = i + 16 < cnt, v3 = i + 24 < cnt;
    int s0 = v0 ? srcsort1[start + i]      : 0;
    int s1 = v1 ? srcsort1[start + i + 8]  : 0;
    int s2 = v2 ? srcsort1[start + i + 16] : 0;
    int s3 = v3 ? srcsort1[start + i + 24] : 0;
    for (;;) {
        float lg0 = esb[s0], lg1 = esb[s1], lg2 = esb[s2], lg3 = esb[s3];
        float4 h0 = *(const float4*)&htb[(size_t)s0*32 + c*4];
        float4 h1 = *(const float4*)&htb[(size_t)s1*32 + c*4];
        float4 h2 = *(const float4*)&htb[(size_t)s2*32 + c*4];
        float4 h3 = *(const float4*)&htb[(size_t)s3*32 + c*4];
        int ni = i + 32;
        bool nv0 = ni      < cnt, nv1 = ni + 8  < cnt,
             nv2 = ni + 16 < cnt, nv3 = ni + 24 < cnt;
        int t0 = nv0 ? srcsort1[start + ni]      : 0;
        int t1 = nv1 ? srcsort1[start + ni + 8]  : 0;
        int t2 = nv2 ? srcsort1[start + ni + 16] : 0;
        int t3 = nv3 ? srcsort1[start + ni + 24] : 0;
        lg0 += edv; lg1 += edv; lg2 += edv; lg3 += edv;
        lg0 = lg0 > 0.f ? lg0 : NEG * lg0;
        lg1 = lg1 > 0.f ? lg1 : NEG * lg1;
        lg2 = lg2 > 0.f ? lg2 : NEG * lg2;
        lg3 = lg3 > 0.f ? lg3 : NEG * lg3;
        float w0 = v0 ? __expf(lg0) : 0.f;
        float w1 = v1 ? __expf(lg1) : 0.f;
        float w2 = v2 ? __expf(lg2) : 0.f;
        float w3 = v3 ? __expf(lg3) : 0.f;
        ax = fmaf(w0, h0.x, ax); ay = fmaf(w0, h0.y, ay);
        az = fmaf(w0, h0.z, az); aw = fmaf(w0, h0.w, aw);
        ax = fmaf(w1, h1.x, ax); ay = fmaf(w1, h1.y, ay);
        az = fmaf(w1, h1.z, az); aw = fmaf(w1, h1.w, aw);
        ax = fmaf(w2, h2.x, ax); ay = fmaf(w2, h2.y, ay);
        az = fmaf(w2, h2.z, az); aw = fmaf(w2, h2.w, aw);
        ax = fmaf(w3, h3.x, ax); ay = fmaf(w3, h3.y, ay);
        az = fmaf(w3, h3.z, az); aw = fmaf(w3, h3.w, aw);
        wsum += (w0 + w1) + (w2 + w3);
        i = ni; s0 = t0; s1 = t1; s2 = t2; s3 = t3;
        v0 = nv0; v1 = nv1; v2 = nv2; v3 = nv3;
        if (i >= cnt) break;
    }
    ax += __shfl_xor(ax, 8); ax += __shfl_xor(ax, 16); ax += __shfl_xor(ax, 32);
    ay += __shfl_xor(ay, 8); ay += __shfl_xor(ay, 16); ay += __shfl_xor(ay, 32);
    az += __shfl_xor(az, 8); az += __shfl_xor(az, 16); az += __shfl_xor(az, 32);
    aw += __shfl_xor(aw, 8); aw += __shfl_xor(aw, 16); aw += __shfl_xor(aw, 32);
    wsum += __shfl_xor(wsum, 8); wsum += __shfl_xor(wsum, 16); wsum += __shfl_xor(wsum, 32);
    if (grp == 0) {
        float inv = cnt > 0 ? 1.f / wsum : 0.f;
        float4 bb = *(const float4*)&b2[c*4];
        float4 o;
        o.x = ax*inv + bb.x; o.y = ay*inv + bb.y;
        o.z = az*inv + bb.z; o.w = aw*inv + bb.w;
        *(float4*)&outp[((size_t)(b*ND1 + d))*32 + c*4] = o;
    }
}

extern "C" void kernel_launch(void* const* d_in, const int* in_sizes, int n_in,
                              void* d_out, int out_size, void* d_ws, size_t ws_size,
                              hipStream_t stream) {
    const float* x        = (const float*)d_in[0];
    const int*   n_id0    = (const int*)d_in[1];
    const int*   res0     = (const int*)d_in[2];
    const int*   esrc0    = (const int*)d_in[3];
    const int*   edst0    = (const int*)d_in[4];
    const int*   res1     = (const int*)d_in[5];
    const int*   esrc1    = (const int*)d_in[6];
    const int*   edst1    = (const int*)d_in[7];
    const float* W1       = (const float*)d_in[8];
    const float* a_src1   = (const float*)d_in[9];
    const float* a_dst1   = (const float*)d_in[10];
    const float* b1       = (const float*)d_in[11];
    const float* W2       = (const float*)d_in[12];
    const float* a_src2   = (const float*)d_in[13];
    const float* a_dst2   = (const float*)d_in[14];
    const float* b2       = (const float*)d_in[15];
    float* outp = (float*)d_out;

    char* base = (char*)d_ws;
    unsigned short* ht1b = (unsigned short*)base;            // 120000*64*2  = 15,360,000 B
    float* es1  = (float*)(base + 15360000);                 // 960,000 f
    float* ed1  = es1 + 960000;                              // 960,000 f
    float* ht2  = ed1 + 960000;                              // 1,920,000 f
    float* es2  = ht2 + 1920000;                             // 60,000 f
    float* ed2  = es2 + 60000;                               // 60,000 f
    // cur0|cur1 contiguous so one memsetAsync zeroes both
    int* cur0     = (int*)(ed2 + 60000);                     // 15000
    int* cur1     = cur0 + ND0;                              // 7500
    int* srcsort0 = cur1 + ND1;                              // 15000*64 = 960,000
    int* srcsort1 = srcsort0 + ND0*CAP;                      // 7500*64  = 480,000
    // total ~37 MB

    hipMemsetAsync(cur0, 0, (ND0 + ND1) * sizeof(int), stream);
    kA_gemm_scat<<<K1B + SB4, 256, 0, stream>>>(x, n_id0, W1, a_src1, a_dst1,
                                                ht1b, es1, ed1,
                                                esrc0, edst0, esrc1, edst1,
                                                cur0, cur1, srcsort0, srcsort1);
    k3_agg1_node2<<<NB*(ND0/4), 256, 0, stream>>>(srcsort0, cur0, res0, es1, ed1, ht1b, b1,
                                                  W2, a_src2, a_dst2, ht2, es2, ed2);
    k7_agg2<<<7504, 256, 0, stream>>>(srcsort1, cur1, res1, es2, ed2, ht2, b2, outp);
}

// Round 4
// 196.923 us; speedup vs baseline: 1.2649x; 1.0370x over previous
//
#include <hip/hip_runtime.h>

#define NB 4
#define NT 40000
#define NS0 30000
#define ND0 15000
#define NE0 360000
#define ND1 7500
#define NE1 180000
#define NEG 0.2f

#define CAP 64                            // bucket capacity per dst (avg deg 24)
#define K1B ((NB*NS0)/64)                 // 1875 GEMM blocks
#define HB  ((NE0 + NE1 + 255)/256)       // 2110 scatter blocks (1 edge/thread, tail)

typedef __attribute__((ext_vector_type(8))) short bf8;
typedef __attribute__((ext_vector_type(4))) float f4;

__device__ __forceinline__ unsigned short f2bf(float f) {
    unsigned u = __float_as_uint(f);
    u += 0x7FFF + ((u >> 16) & 1);          // round-to-nearest-even
    return (unsigned short)(u >> 16);
}
// packed bf16 pair in a uint: low ushort = even channel, high = odd channel
__device__ __forceinline__ float bf_lo(unsigned u) { return __uint_as_float(u << 16); }
__device__ __forceinline__ float bf_hi(unsigned u) { return __uint_as_float(u & 0xFFFF0000u); }

// -------- fused: layer-1 MFMA GEMM + bucket scatter (CSR without scan) -----
// blocks [0, K1B): node transform; blocks [K1B, K1B+HB): edge scatter into
// fixed-capacity (CAP=64) per-dst buckets. Scatter at the TAIL (R1 ordering:
// 49.6 us vs 53.1 with scatter-first — measured R1 vs R3).
__global__ __launch_bounds__(256) void kA_gemm_scat(
        const float* __restrict__ x, const int* __restrict__ n_id0,
        const float* __restrict__ W1, const float* __restrict__ a_src,
        const float* __restrict__ a_dst,
        unsigned short* __restrict__ ht1b, float* __restrict__ es1, float* __restrict__ ed1,
        const int* __restrict__ esrc0, const int* __restrict__ edst0,
        const int* __restrict__ esrc1, const int* __restrict__ edst1,
        int* __restrict__ cur0, int* __restrict__ cur1,
        int* __restrict__ srcsort0, int* __restrict__ srcsort1) {
    __shared__ unsigned short xtb[64*72];
    __shared__ unsigned short wtb[64*72];
    __shared__ float asl[64], adl[64];
    if (blockIdx.x >= K1B) {                 // ---- scatter part ----
        int t = (blockIdx.x - K1B) * 256 + threadIdx.x;
        if (t < NE0) {
            int d = edst0[t];
            int pos = atomicAdd(&cur0[d], 1);
            if (pos < CAP) srcsort0[d*CAP + pos] = esrc0[t];
        } else if (t < NE0 + NE1) {
            int e = t - NE0;
            int d = edst1[e];
            int pos = atomicAdd(&cur1[d], 1);
            if (pos < CAP) srcsort1[d*CAP + pos] = esrc1[e];
        }
        return;
    }
    // ---- GEMM part ----
    int bid = blockIdx.x;
    int t = threadIdx.x;
    {
        int k = t >> 2, nb = (t & 3) * 16;
        const float* wrow = &W1[k*64 + nb];
        #pragma unroll
        for (int j = 0; j < 16; j += 4) {
            float4 v = *(const float4*)&wrow[j];
            wtb[(nb+j+0)*72 + k] = f2bf(v.x);
            wtb[(nb+j+1)*72 + k] = f2bf(v.y);
            wtb[(nb+j+2)*72 + k] = f2bf(v.z);
            wtb[(nb+j+3)*72 + k] = f2bf(v.w);
        }
    }
    if (t < 64) { asl[t] = a_src[t]; adl[t] = a_dst[t]; }
    {
        int rr = t & 63;
        int q4 = t >> 6;
        int row_s = bid * 64 + rr;                  // < 120000 (1875*64)
        int bs = row_s / NS0;
        int ns = row_s - bs * NS0;
        const float* xrow = x + ((size_t)(bs * NT + n_id0[ns])) * 64;
        #pragma unroll
        for (int j = 0; j < 4; ++j) {
            int k = q4 * 16 + j * 4;
            float4 v = *(const float4*)&xrow[k];
            ushort4 u;
            u.x = f2bf(v.x); u.y = f2bf(v.y); u.z = f2bf(v.z); u.w = f2bf(v.w);
            *(ushort4*)&xtb[rr*72 + k] = u;
        }
    }
    __syncthreads();
    int w = t >> 6, lane = t & 63, quad = lane >> 4, cl = lane & 15;
    int arow = 16*w + cl;
    bf8 a0 = *(const bf8*)&xtb[arow*72 + quad*8];        // A[m=cl][k=quad*8+j]
    bf8 a1 = *(const bf8*)&xtb[arow*72 + 32 + quad*8];   // k+32
    f4 acc[4];
    #pragma unroll
    for (int sub = 0; sub < 4; ++sub) {
        int n = sub*16 + cl;
        bf8 b0 = *(const bf8*)&wtb[n*72 + quad*8];       // B[k][n=cl]
        bf8 b1v = *(const bf8*)&wtb[n*72 + 32 + quad*8];
        f4 c = {0.f, 0.f, 0.f, 0.f};
        c = __builtin_amdgcn_mfma_f32_16x16x32_bf16(a0, b0, c, 0, 0, 0);
        c = __builtin_amdgcn_mfma_f32_16x16x32_bf16(a1, b1v, c, 0, 0, 0);
        acc[sub] = c;
    }
    int rbase = bid*64 + 16*w + quad*4;
    #pragma unroll
    for (int sub = 0; sub < 4; ++sub)
        #pragma unroll
        for (int r = 0; r < 4; ++r)
            ht1b[(size_t)(rbase + r)*64 + sub*16 + cl] = f2bf(acc[sub][r]);
    #pragma unroll
    for (int r = 0; r < 4; ++r) {
        #pragma unroll
        for (int sub = 0; sub < 4; ++sub) {
            int col = sub*16 + cl;
            float ps = acc[sub][r] * asl[col];
            float pd = acc[sub][r] * adl[col];
            ps += __shfl_xor(ps, 1); ps += __shfl_xor(ps, 2); ps += __shfl_xor(ps, 4);
            pd += __shfl_xor(pd, 1); pd += __shfl_xor(pd, 2); pd += __shfl_xor(pd, 4);
            if ((cl & 7) == 0) {
                int h = sub*2 + (cl >> 3);
                es1[(rbase + r)*8 + h] = ps;
                ed1[(rbase + r)*8 + h] = pd;
            }
        }
    }
}

// -------- fused: layer-1 per-dst aggregation + layer-2 node transform ------
// Epilogue restructured to cut DS-pipe ops ~60%:
//  * butterfly reduce-scatter: 7 shfl (was 24); lane (grp,c) ends with
//    channel c*8+grp -> ELU is 1 exp/lane on all 64 lanes (was 8 serial
//    exps on 8 lanes)
//  * W2 transposed in LDS (W2t[c2][k], pad 68) -> W2 matvec reads are
//    16x ds_read_b128 (was 64x ds_read_b32)
__global__ __launch_bounds__(256) void k3_agg1_node2(
        const int* __restrict__ srcsort0, const int* __restrict__ cur0,
        const int* __restrict__ res0,
        const float* __restrict__ es1, const float* __restrict__ ed1,
        const unsigned short* __restrict__ ht1b, const float* __restrict__ b1,
        const float* __restrict__ W2, const float* __restrict__ a_src2,
        const float* __restrict__ a_dst2,
        float* __restrict__ ht2, float* __restrict__ es2, float* __restrict__ ed2) {
    __shared__ float W2t[32][68];          // W2t[c2][k] = W2[k][c2]; 68 pad: 16B-aligned rows, 17-bank stride
    __shared__ float as2[32], ad2[32];
    __shared__ float b1l[64];
    __shared__ float hsh[4][64];           // per-wave h(d)
    int t = threadIdx.x;
    {   // coalesced W2 read (8 KB) + transposed LDS write
        float4 v0 = *(const float4*)&W2[t*8];
        float4 v1 = *(const float4*)&W2[t*8 + 4];
        int k = t >> 2, c = (t & 3) * 8;
        W2t[c+0][k] = v0.x; W2t[c+1][k] = v0.y; W2t[c+2][k] = v0.z; W2t[c+3][k] = v0.w;
        W2t[c+4][k] = v1.x; W2t[c+5][k] = v1.y; W2t[c+6][k] = v1.z; W2t[c+7][k] = v1.w;
    }
    if (t < 32) { as2[t] = a_src2[t]; ad2[t] = a_dst2[t]; }
    if (t < 64) b1l[t] = b1[t];
    __syncthreads();                       // only barrier: staging ready
    int xcd = blockIdx.x & 7;
    int b = xcd >> 1;                      // batch pinned to XCD pair
    int chunk = (blockIdx.x >> 3) * 2 + (xcd & 1);   // 0..3749 (bijective)
    int wv = t >> 6;
    int d = chunk * 4 + wv;
    int lane = t & 63;
    int grp = lane >> 3;                   // edge slot 0..7
    int c = lane & 7;                      // head index; channels 8c..8c+7
    int dn = res0[d];
    float edv = ed1[(b*NS0 + dn)*8 + c];
    int start = d * CAP;
    int cnt = cur0[d];
    const float* esb = es1 + (size_t)b*NS0*8;
    const unsigned short* htb = ht1b + (size_t)b*NS0*64;
    float acc[8] = {};
    float wsum = 0.f;
    int i = grp;
    bool v0 = i      < cnt, v1 = i + 8  < cnt,
         v2 = i + 16 < cnt, v3 = i + 24 < cnt;
    int s0 = v0 ? srcsort0[start + i]      : 0;
    int s1 = v1 ? srcsort0[start + i + 8]  : 0;
    int s2 = v2 ? srcsort0[start + i + 16] : 0;
    int s3 = v3 ? srcsort0[start + i + 24] : 0;
    for (;;) {
        float e0 = esb[s0*8 + c], e1 = esb[s1*8 + c];
        float e2 = esb[s2*8 + c], e3 = esb[s3*8 + c];
        uint4 h0 = *(const uint4*)&htb[(size_t)s0*64 + c*8];
        uint4 h1 = *(const uint4*)&htb[(size_t)s1*64 + c*8];
        uint4 h2 = *(const uint4*)&htb[(size_t)s2*64 + c*8];
        uint4 h3 = *(const uint4*)&htb[(size_t)s3*64 + c*8];
        int ni = i + 32;
        bool nv0 = false, nv1 = false, nv2 = false, nv3 = false;
        int t0 = 0, t1 = 0, t2 = 0, t3 = 0;
        if (ni < cnt) {                    // wave-uniform: skip prefetch on final iter
            nv0 = true;            nv1 = ni + 8  < cnt;
            nv2 = ni + 16 < cnt;   nv3 = ni + 24 < cnt;
            t0 =       srcsort0[start + ni];
            t1 = nv1 ? srcsort0[start + ni + 8]  : 0;
            t2 = nv2 ? srcsort0[start + ni + 16] : 0;
            t3 = nv3 ? srcsort0[start + ni + 24] : 0;
        }
        e0 += edv; e1 += edv; e2 += edv; e3 += edv;
        e0 = e0 > 0.f ? e0 : NEG * e0;
        e1 = e1 > 0.f ? e1 : NEG * e1;
        e2 = e2 > 0.f ? e2 : NEG * e2;
        e3 = e3 > 0.f ? e3 : NEG * e3;
        float w0 = v0 ? __expf(e0) : 0.f;
        float w1 = v1 ? __expf(e1) : 0.f;
        float w2 = v2 ? __expf(e2) : 0.f;
        float w3 = v3 ? __expf(e3) : 0.f;
        acc[0] = fmaf(w0, bf_lo(h0.x), acc[0]); acc[1] = fmaf(w0, bf_hi(h0.x), acc[1]);
        acc[2] = fmaf(w0, bf_lo(h0.y), acc[2]); acc[3] = fmaf(w0, bf_hi(h0.y), acc[3]);
        acc[4] = fmaf(w0, bf_lo(h0.z), acc[4]); acc[5] = fmaf(w0, bf_hi(h0.z), acc[5]);
        acc[6] = fmaf(w0, bf_lo(h0.w), acc[6]); acc[7] = fmaf(w0, bf_hi(h0.w), acc[7]);
        acc[0] = fmaf(w1, bf_lo(h1.x), acc[0]); acc[1] = fmaf(w1, bf_hi(h1.x), acc[1]);
        acc[2] = fmaf(w1, bf_lo(h1.y), acc[2]); acc[3] = fmaf(w1, bf_hi(h1.y), acc[3]);
        acc[4] = fmaf(w1, bf_lo(h1.z), acc[4]); acc[5] = fmaf(w1, bf_hi(h1.z), acc[5]);
        acc[6] = fmaf(w1, bf_lo(h1.w), acc[6]); acc[7] = fmaf(w1, bf_hi(h1.w), acc[7]);
        acc[0] = fmaf(w2, bf_lo(h2.x), acc[0]); acc[1] = fmaf(w2, bf_hi(h2.x), acc[1]);
        acc[2] = fmaf(w2, bf_lo(h2.y), acc[2]); acc[3] = fmaf(w2, bf_hi(h2.y), acc[3]);
        acc[4] = fmaf(w2, bf_lo(h2.z), acc[4]); acc[5] = fmaf(w2, bf_hi(h2.z), acc[5]);
        acc[6] = fmaf(w2, bf_lo(h2.w), acc[6]); acc[7] = fmaf(w2, bf_hi(h2.w), acc[7]);
        acc[0] = fmaf(w3, bf_lo(h3.x), acc[0]); acc[1] = fmaf(w3, bf_hi(h3.x), acc[1]);
        acc[2] = fmaf(w3, bf_lo(h3.y), acc[2]); acc[3] = fmaf(w3, bf_hi(h3.y), acc[3]);
        acc[4] = fmaf(w3, bf_lo(h3.z), acc[4]); acc[5] = fmaf(w3, bf_hi(h3.z), acc[5]);
        acc[6] = fmaf(w3, bf_lo(h3.w), acc[6]); acc[7] = fmaf(w3, bf_hi(h3.w), acc[7]);
        wsum += (w0 + w1) + (w2 + w3);
        i = ni; s0 = t0; s1 = t1; s2 = t2; s3 = t3;
        v0 = nv0; v1 = nv1; v2 = nv2; v3 = nv3;
        if (i >= cnt) break;
    }
    // ---- butterfly reduce-scatter over the 8 edge-slot groups ----
    // After 3 rounds lane (grp,c) holds the full sum for channel c*8+grp.
    int g0 = grp & 1, g1 = (grp >> 1) & 1, g2 = grp >> 2;
    float n0, n1, n2, n3;
    {
        float s, r;
        s = g0 ? acc[0] : acc[1]; r = __shfl_xor(s, 8);  n0 = (g0 ? acc[1] : acc[0]) + r;
        s = g0 ? acc[2] : acc[3]; r = __shfl_xor(s, 8);  n1 = (g0 ? acc[3] : acc[2]) + r;
        s = g0 ? acc[4] : acc[5]; r = __shfl_xor(s, 8);  n2 = (g0 ? acc[5] : acc[4]) + r;
        s = g0 ? acc[6] : acc[7]; r = __shfl_xor(s, 8);  n3 = (g0 ? acc[7] : acc[6]) + r;
    }
    float m0, m1;
    {
        float s, r;
        s = g1 ? n0 : n1; r = __shfl_xor(s, 16); m0 = (g1 ? n1 : n0) + r;
        s = g1 ? n2 : n3; r = __shfl_xor(s, 16); m1 = (g1 ? n3 : n2) + r;
    }
    float fin;
    {
        float s = g2 ? m0 : m1; float r = __shfl_xor(s, 32); fin = (g2 ? m1 : m0) + r;
    }
    wsum += __shfl_xor(wsum, 8); wsum += __shfl_xor(wsum, 16); wsum += __shfl_xor(wsum, 32);
    float inv = cnt > 0 ? 1.f / wsum : 0.f;
    float o = fin * inv + b1l[(c << 3) | grp];
    o = o > 0.f ? o : __expf(o) - 1.f;     // ELU: 1 exp per lane, all 64 lanes
    hsh[wv][(c << 3) | grp] = o;
    // hsh[wv] written and read by the SAME wave -> lgkmcnt ordering suffices.
    // ---- layer-2 node transform: out[c2] = sum_k h[k] * W2t[c2][k] ----
    int c2 = lane & 31, half = lane >> 5;
    const float4* hp = (const float4*)&hsh[wv][half * 32];
    const float4* wp = (const float4*)&W2t[c2][half * 32];
    float acc2 = 0.f;
    #pragma unroll
    for (int q = 0; q < 8; ++q) {
        float4 hv = hp[q];
        float4 w4 = wp[q];
        acc2 = fmaf(hv.x, w4.x, acc2); acc2 = fmaf(hv.y, w4.y, acc2);
        acc2 = fmaf(hv.z, w4.z, acc2); acc2 = fmaf(hv.w, w4.w, acc2);
    }
    acc2 += __shfl_xor(acc2, 32);          // lanes 0..31 (and 32..63) hold out[c2]
    float ps = acc2 * as2[c2];
    float pd = acc2 * ad2[c2];
    ps += __shfl_xor(ps, 1); ps += __shfl_xor(ps, 2); ps += __shfl_xor(ps, 4);
    ps += __shfl_xor(ps, 8); ps += __shfl_xor(ps, 16);
    pd += __shfl_xor(pd, 1); pd += __shfl_xor(pd, 2); pd += __shfl_xor(pd, 4);
    pd += __shfl_xor(pd, 8); pd += __shfl_xor(pd, 16);
    int row = b*ND0 + d;
    if (half == 0) ht2[(size_t)row*32 + c2] = acc2;   // coalesced 128 B
    if (lane == 0) { es2[row] = ps; ed2[row] = pd; }
}

// ---------------- layer 2 per-dst aggregation (4-deep pipeline) ------------
// Same XCD-pair batch pinning; grid padded to 7504 with chunk guard (7500%8!=0).
__global__ __launch_bounds__(256) void k7_agg2(
        const int* __restrict__ srcsort1, const int* __restrict__ cur1,
        const int* __restrict__ res1,
        const float* __restrict__ es2, const float* __restrict__ ed2,
        const float* __restrict__ ht2, const float* __restrict__ b2,
        float* __restrict__ outp) {
    int xcd = blockIdx.x & 7;
    int b = xcd >> 1;
    int chunk = (blockIdx.x >> 3) * 2 + (xcd & 1);
    if (chunk >= ND1/4) return;            // pad blocks (grid 7504)
    int d = chunk * 4 + (threadIdx.x >> 6);
    int lane = threadIdx.x & 63;
    int grp = lane >> 3;                   // edge slot 0..7
    int c = lane & 7;                      // channel quad: channels 4c..4c+3
    int dn = res1[d];
    float edv = ed2[b*ND0 + dn];
    int start = d * CAP;
    int cnt = cur1[d];
    const float* esb = es2 + (size_t)b*ND0;
    const float* htb = ht2 + (size_t)b*ND0*32;
    float ax = 0.f, ay = 0.f, az = 0.f, aw = 0.f, wsum = 0.f;
    int i = grp;
    bool v0 = i      < cnt, v1 = i + 8  < cnt,
         v2 = i + 16 < cnt, v3 = i + 24 < cnt;
    int s0 = v0 ? srcsort1[start + i]      : 0;
    int s1 = v1 ? srcsort1[start + i + 8]  : 0;
    int s2 = v2 ? srcsort1[start + i + 16] : 0;
    int s3 = v3 ? srcsort1[start + i + 24] : 0;
    for (;;) {
        float lg0 = esb[s0], lg1 = esb[s1], lg2 = esb[s2], lg3 = esb[s3];
        float4 h0 = *(const float4*)&htb[(size_t)s0*32 + c*4];
        float4 h1 = *(const float4*)&htb[(size_t)s1*32 + c*4];
        float4 h2 = *(const float4*)&htb[(size_t)s2*32 + c*4];
        float4 h3 = *(const float4*)&htb[(size_t)s3*32 + c*4];
        int ni = i + 32;
        bool nv0 = false, nv1 = false, nv2 = false, nv3 = false;
        int t0 = 0, t1 = 0, t2 = 0, t3 = 0;
        if (ni < cnt) {                    // wave-uniform: skip prefetch on final iter
            nv0 = true;            nv1 = ni + 8  < cnt;
            nv2 = ni + 16 < cnt;   nv3 = ni + 24 < cnt;
            t0 =       srcsort1[start + ni];
            t1 = nv1 ? srcsort1[start + ni + 8]  : 0;
            t2 = nv2 ? srcsort1[start + ni + 16] : 0;
            t3 = nv3 ? srcsort1[start + ni + 24] : 0;
        }
        lg0 += edv; lg1 += edv; lg2 += edv; lg3 += edv;
        lg0 = lg0 > 0.f ? lg0 : NEG * lg0;
        lg1 = lg1 > 0.f ? lg1 : NEG * lg1;
        lg2 = lg2 > 0.f ? lg2 : NEG * lg2;
        lg3 = lg3 > 0.f ? lg3 : NEG * lg3;
        float w0 = v0 ? __expf(lg0) : 0.f;
        float w1 = v1 ? __expf(lg1) : 0.f;
        float w2 = v2 ? __expf(lg2) : 0.f;
        float w3 = v3 ? __expf(lg3) : 0.f;
        ax = fmaf(w0, h0.x, ax); ay = fmaf(w0, h0.y, ay);
        az = fmaf(w0, h0.z, az); aw = fmaf(w0, h0.w, aw);
        ax = fmaf(w1, h1.x, ax); ay = fmaf(w1, h1.y, ay);
        az = fmaf(w1, h1.z, az); aw = fmaf(w1, h1.w, aw);
        ax = fmaf(w2, h2.x, ax); ay = fmaf(w2, h2.y, ay);
        az = fmaf(w2, h2.z, az); aw = fmaf(w2, h2.w, aw);
        ax = fmaf(w3, h3.x, ax); ay = fmaf(w3, h3.y, ay);
        az = fmaf(w3, h3.z, az); aw = fmaf(w3, h3.w, aw);
        wsum += (w0 + w1) + (w2 + w3);
        i = ni; s0 = t0; s1 = t1; s2 = t2; s3 = t3;
        v0 = nv0; v1 = nv1; v2 = nv2; v3 = nv3;
        if (i >= cnt) break;
    }
    ax += __shfl_xor(ax, 8); ax += __shfl_xor(ax, 16); ax += __shfl_xor(ax, 32);
    ay += __shfl_xor(ay, 8); ay += __shfl_xor(ay, 16); ay += __shfl_xor(ay, 32);
    az += __shfl_xor(az, 8); az += __shfl_xor(az, 16); az += __shfl_xor(az, 32);
    aw += __shfl_xor(aw, 8); aw += __shfl_xor(aw, 16); aw += __shfl_xor(aw, 32);
    wsum += __shfl_xor(wsum, 8); wsum += __shfl_xor(wsum, 16); wsum += __shfl_xor(wsum, 32);
    if (grp == 0) {
        float inv = cnt > 0 ? 1.f / wsum : 0.f;
        float4 bb = *(const float4*)&b2[c*4];
        float4 o;
        o.x = ax*inv + bb.x; o.y = ay*inv + bb.y;
        o.z = az*inv + bb.z; o.w = aw*inv + bb.w;
        *(float4*)&outp[((size_t)(b*ND1 + d))*32 + c*4] = o;
    }
}

extern "C" void kernel_launch(void* const* d_in, const int* in_sizes, int n_in,
                              void* d_out, int out_size, void* d_ws, size_t ws_size,
                              hipStream_t stream) {
    const float* x        = (const float*)d_in[0];
    const int*   n_id0    = (const int*)d_in[1];
    const int*   res0     = (const int*)d_in[2];
    const int*   esrc0    = (const int*)d_in[3];
    const int*   edst0    = (const int*)d_in[4];
    const int*   res1     = (const int*)d_in[5];
    const int*   esrc1    = (const int*)d_in[6];
    const int*   edst1    = (const int*)d_in[7];
    const float* W1       = (const float*)d_in[8];
    const float* a_src1   = (const float*)d_in[9];
    const float* a_dst1   = (const float*)d_in[10];
    const float* b1       = (const float*)d_in[11];
    const float* W2       = (const float*)d_in[12];
    const float* a_src2   = (const float*)d_in[13];
    const float* a_dst2   = (const float*)d_in[14];
    const float* b2       = (const float*)d_in[15];
    float* outp = (float*)d_out;

    char* base = (char*)d_ws;
    unsigned short* ht1b = (unsigned short*)base;            // 120000*64*2  = 15,360,000 B
    float* es1  = (float*)(base + 15360000);                 // 960,000 f
    float* ed1  = es1 + 960000;                              // 960,000 f
    float* ht2  = ed1 + 960000;                              // 1,920,000 f
    float* es2  = ht2 + 1920000;                             // 60,000 f
    float* ed2  = es2 + 60000;                               // 60,000 f
    // cur0|cur1 contiguous so one memsetAsync zeroes both
    int* cur0     = (int*)(ed2 + 60000);                     // 15000
    int* cur1     = cur0 + ND0;                              // 7500
    int* srcsort0 = cur1 + ND1;                              // 15000*64 = 960,000
    int* srcsort1 = srcsort0 + ND0*CAP;                      // 7500*64  = 480,000
    // total ~37 MB

    hipMemsetAsync(cur0, 0, (ND0 + ND1) * sizeof(int), stream);
    kA_gemm_scat<<<K1B + HB, 256, 0, stream>>>(x, n_id0, W1, a_src1, a_dst1,
                                               ht1b, es1, ed1,
                                               esrc0, edst0, esrc1, edst1,
                                               cur0, cur1, srcsort0, srcsort1);
    k3_agg1_node2<<<NB*(ND0/4), 256, 0, stream>>>(srcsort0, cur0, res0, es1, ed1, ht1b, b1,
                                                  W2, a_src2, a_dst2, ht2, es2, ed2);
    k7_agg2<<<7504, 256, 0, stream>>>(srcsort1, cur1, res1, es2, ed2, ht2, b2, outp);
}

// Round 5
// 191.644 us; speedup vs baseline: 1.2997x; 1.0275x over previous
//
#include <hip/hip_runtime.h>

#define NB 4
#define NT 40000
#define NS0 30000
#define ND0 15000
#define NE0 360000
#define ND1 7500
#define NE1 180000
#define NEG 0.2f

#define CAP 64                            // bucket capacity per dst (avg deg 24)
#define K1B ((NB*NS0)/64)                 // 1875 GEMM blocks
#define SB8 ((NE0 + NE1 + 2047)/2048)     // 264 scatter blocks (8 edges/thread)

typedef __attribute__((ext_vector_type(8))) short bf8;
typedef __attribute__((ext_vector_type(4))) float f4;

__device__ __forceinline__ unsigned short f2bf(float f) {
    unsigned u = __float_as_uint(f);
    u += 0x7FFF + ((u >> 16) & 1);          // round-to-nearest-even
    return (unsigned short)(u >> 16);
}
// packed bf16 pair in a uint: low ushort = even channel, high = odd channel
__device__ __forceinline__ float bf_lo(unsigned u) { return __uint_as_float(u << 16); }
__device__ __forceinline__ float bf_hi(unsigned u) { return __uint_as_float(u & 0xFFFF0000u); }

// -------- fused: layer-1 MFMA GEMM + bucket scatter (CSR without scan) -----
// blocks [0, K1B): node transform; blocks [K1B, K1B+SB8): edge scatter,
// 8 edges/thread (8 independent atomic->store chains per lane for latency
// hiding). Scatter stays at the TAIL (R1 vs R2/R3: tail measured faster).
__global__ __launch_bounds__(256) void kA_gemm_scat(
        const float* __restrict__ x, const int* __restrict__ n_id0,
        const float* __restrict__ W1, const float* __restrict__ a_src,
        const float* __restrict__ a_dst,
        unsigned short* __restrict__ ht1b, float* __restrict__ es1, float* __restrict__ ed1,
        const int* __restrict__ esrc0, const int* __restrict__ edst0,
        const int* __restrict__ esrc1, const int* __restrict__ edst1,
        int* __restrict__ cur0, int* __restrict__ cur1,
        int* __restrict__ srcsort0, int* __restrict__ srcsort1) {
    __shared__ unsigned short xtb[64*72];
    __shared__ unsigned short wtb[64*72];
    __shared__ float asl[64], adl[64];
    if (blockIdx.x >= K1B) {                 // ---- scatter part ----
        int base = (blockIdx.x - K1B) * 2048 + threadIdx.x;
        #pragma unroll
        for (int p = 0; p < 8; ++p) {
            int t = base + p * 256;
            if (t < NE0) {
                int d = edst0[t];
                int pos = atomicAdd(&cur0[d], 1);
                if (pos < CAP) srcsort0[d*CAP + pos] = esrc0[t];
            } else if (t < NE0 + NE1) {
                int e = t - NE0;
                int d = edst1[e];
                int pos = atomicAdd(&cur1[d], 1);
                if (pos < CAP) srcsort1[d*CAP + pos] = esrc1[e];
            }
        }
        return;
    }
    // ---- GEMM part ----
    int bid = blockIdx.x;
    int t = threadIdx.x;
    {
        int k = t >> 2, nb = (t & 3) * 16;
        const float* wrow = &W1[k*64 + nb];
        #pragma unroll
        for (int j = 0; j < 16; j += 4) {
            float4 v = *(const float4*)&wrow[j];
            wtb[(nb+j+0)*72 + k] = f2bf(v.x);
            wtb[(nb+j+1)*72 + k] = f2bf(v.y);
            wtb[(nb+j+2)*72 + k] = f2bf(v.z);
            wtb[(nb+j+3)*72 + k] = f2bf(v.w);
        }
    }
    if (t < 64) { asl[t] = a_src[t]; adl[t] = a_dst[t]; }
    {
        // Cooperative gather: 4 consecutive lanes share one row; per load
        // instruction a wave touches 16 rows x 64 contiguous bytes (16 cache
        // lines) instead of 64 rows x 16 B (64 lines). Also drops the LDS
        // staging-write conflict from 8-way to <=4-way (rows per wave: 16,
        // bank stride 36 dwords -> only r,r+8 collide).
        int r   = t >> 2;                     // 0..63 row within block
        int sub = t & 3;                      // float4 slot within 64B chunk
        int row_s = bid * 64 + r;             // < 120000 (1875*64)
        int bs = row_s / NS0;
        int ns = row_s - bs * NS0;
        const float* xrow = x + ((size_t)(bs * NT + n_id0[ns])) * 64;
        #pragma unroll
        for (int j = 0; j < 4; ++j) {
            int kf = (sub + j*4) * 4;         // float index of this float4
            float4 v = *(const float4*)&xrow[kf];
            ushort4 u;
            u.x = f2bf(v.x); u.y = f2bf(v.y); u.z = f2bf(v.z); u.w = f2bf(v.w);
            *(ushort4*)&xtb[r*72 + kf] = u;
        }
    }
    __syncthreads();
    int w = t >> 6, lane = t & 63, quad = lane >> 4, cl = lane & 15;
    int arow = 16*w + cl;
    bf8 a0 = *(const bf8*)&xtb[arow*72 + quad*8];        // A[m=cl][k=quad*8+j]
    bf8 a1 = *(const bf8*)&xtb[arow*72 + 32 + quad*8];   // k+32
    f4 acc[4];
    #pragma unroll
    for (int sub = 0; sub < 4; ++sub) {
        int n = sub*16 + cl;
        bf8 b0 = *(const bf8*)&wtb[n*72 + quad*8];       // B[k][n=cl]
        bf8 b1v = *(const bf8*)&wtb[n*72 + 32 + quad*8];
        f4 c = {0.f, 0.f, 0.f, 0.f};
        c = __builtin_amdgcn_mfma_f32_16x16x32_bf16(a0, b0, c, 0, 0, 0);
        c = __builtin_amdgcn_mfma_f32_16x16x32_bf16(a1, b1v, c, 0, 0, 0);
        acc[sub] = c;
    }
    int rbase = bid*64 + 16*w + quad*4;
    #pragma unroll
    for (int sub = 0; sub < 4; ++sub)
        #pragma unroll
        for (int r = 0; r < 4; ++r)
            ht1b[(size_t)(rbase + r)*64 + sub*16 + cl] = f2bf(acc[sub][r]);
    #pragma unroll
    for (int r = 0; r < 4; ++r) {
        #pragma unroll
        for (int sub = 0; sub < 4; ++sub) {
            int col = sub*16 + cl;
            float ps = acc[sub][r] * asl[col];
            float pd = acc[sub][r] * adl[col];
            ps += __shfl_xor(ps, 1); ps += __shfl_xor(ps, 2); ps += __shfl_xor(ps, 4);
            pd += __shfl_xor(pd, 1); pd += __shfl_xor(pd, 2); pd += __shfl_xor(pd, 4);
            if ((cl & 7) == 0) {
                int h = sub*2 + (cl >> 3);
                es1[(rbase + r)*8 + h] = ps;
                ed1[(rbase + r)*8 + h] = pd;
            }
        }
    }
}

// -------- fused: layer-1 per-dst aggregation + layer-2 node transform ------
// (unchanged from R3 — dropped out of top-5 after the epilogue restructure)
__global__ __launch_bounds__(256) void k3_agg1_node2(
        const int* __restrict__ srcsort0, const int* __restrict__ cur0,
        const int* __restrict__ res0,
        const float* __restrict__ es1, const float* __restrict__ ed1,
        const unsigned short* __restrict__ ht1b, const float* __restrict__ b1,
        const float* __restrict__ W2, const float* __restrict__ a_src2,
        const float* __restrict__ a_dst2,
        float* __restrict__ ht2, float* __restrict__ es2, float* __restrict__ ed2) {
    __shared__ float W2t[32][68];          // W2t[c2][k] = W2[k][c2]
    __shared__ float as2[32], ad2[32];
    __shared__ float b1l[64];
    __shared__ float hsh[4][64];           // per-wave h(d)
    int t = threadIdx.x;
    {   // coalesced W2 read (8 KB) + transposed LDS write
        float4 v0 = *(const float4*)&W2[t*8];
        float4 v1 = *(const float4*)&W2[t*8 + 4];
        int k = t >> 2, c = (t & 3) * 8;
        W2t[c+0][k] = v0.x; W2t[c+1][k] = v0.y; W2t[c+2][k] = v0.z; W2t[c+3][k] = v0.w;
        W2t[c+4][k] = v1.x; W2t[c+5][k] = v1.y; W2t[c+6][k] = v1.z; W2t[c+7][k] = v1.w;
    }
    if (t < 32) { as2[t] = a_src2[t]; ad2[t] = a_dst2[t]; }
    if (t < 64) b1l[t] = b1[t];
    __syncthreads();                       // only barrier: staging ready
    int xcd = blockIdx.x & 7;
    int b = xcd >> 1;                      // batch pinned to XCD pair
    int chunk = (blockIdx.x >> 3) * 2 + (xcd & 1);   // 0..3749 (bijective)
    int wv = t >> 6;
    int d = chunk * 4 + wv;
    int lane = t & 63;
    int grp = lane >> 3;                   // edge slot 0..7
    int c = lane & 7;                      // head index; channels 8c..8c+7
    int dn = res0[d];
    float edv = ed1[(b*NS0 + dn)*8 + c];
    int start = d * CAP;
    int cnt = cur0[d];
    const float* esb = es1 + (size_t)b*NS0*8;
    const unsigned short* htb = ht1b + (size_t)b*NS0*64;
    float acc[8] = {};
    float wsum = 0.f;
    int i = grp;
    bool v0 = i      < cnt, v1 = i + 8  < cnt,
         v2 = i + 16 < cnt, v3 = i + 24 < cnt;
    int s0 = v0 ? srcsort0[start + i]      : 0;
    int s1 = v1 ? srcsort0[start + i + 8]  : 0;
    int s2 = v2 ? srcsort0[start + i + 16] : 0;
    int s3 = v3 ? srcsort0[start + i + 24] : 0;
    for (;;) {
        float e0 = esb[s0*8 + c], e1 = esb[s1*8 + c];
        float e2 = esb[s2*8 + c], e3 = esb[s3*8 + c];
        uint4 h0 = *(const uint4*)&htb[(size_t)s0*64 + c*8];
        uint4 h1 = *(const uint4*)&htb[(size_t)s1*64 + c*8];
        uint4 h2 = *(const uint4*)&htb[(size_t)s2*64 + c*8];
        uint4 h3 = *(const uint4*)&htb[(size_t)s3*64 + c*8];
        int ni = i + 32;
        bool nv0 = false, nv1 = false, nv2 = false, nv3 = false;
        int t0 = 0, t1 = 0, t2 = 0, t3 = 0;
        if (ni < cnt) {                    // wave-uniform: skip prefetch on final iter
            nv0 = true;            nv1 = ni + 8  < cnt;
            nv2 = ni + 16 < cnt;   nv3 = ni + 24 < cnt;
            t0 =       srcsort0[start + ni];
            t1 = nv1 ? srcsort0[start + ni + 8]  : 0;
            t2 = nv2 ? srcsort0[start + ni + 16] : 0;
            t3 = nv3 ? srcsort0[start + ni + 24] : 0;
        }
        e0 += edv; e1 += edv; e2 += edv; e3 += edv;
        e0 = e0 > 0.f ? e0 : NEG * e0;
        e1 = e1 > 0.f ? e1 : NEG * e1;
        e2 = e2 > 0.f ? e2 : NEG * e2;
        e3 = e3 > 0.f ? e3 : NEG * e3;
        float w0 = v0 ? __expf(e0) : 0.f;
        float w1 = v1 ? __expf(e1) : 0.f;
        float w2 = v2 ? __expf(e2) : 0.f;
        float w3 = v3 ? __expf(e3) : 0.f;
        acc[0] = fmaf(w0, bf_lo(h0.x), acc[0]); acc[1] = fmaf(w0, bf_hi(h0.x), acc[1]);
        acc[2] = fmaf(w0, bf_lo(h0.y), acc[2]); acc[3] = fmaf(w0, bf_hi(h0.y), acc[3]);
        acc[4] = fmaf(w0, bf_lo(h0.z), acc[4]); acc[5] = fmaf(w0, bf_hi(h0.z), acc[5]);
        acc[6] = fmaf(w0, bf_lo(h0.w), acc[6]); acc[7] = fmaf(w0, bf_hi(h0.w), acc[7]);
        acc[0] = fmaf(w1, bf_lo(h1.x), acc[0]); acc[1] = fmaf(w1, bf_hi(h1.x), acc[1]);
        acc[2] = fmaf(w1, bf_lo(h1.y), acc[2]); acc[3] = fmaf(w1, bf_hi(h1.y), acc[3]);
        acc[4] = fmaf(w1, bf_lo(h1.z), acc[4]); acc[5] = fmaf(w1, bf_hi(h1.z), acc[5]);
        acc[6] = fmaf(w1, bf_lo(h1.w), acc[6]); acc[7] = fmaf(w1, bf_hi(h1.w), acc[7]);
        acc[0] = fmaf(w2, bf_lo(h2.x), acc[0]); acc[1] = fmaf(w2, bf_hi(h2.x), acc[1]);
        acc[2] = fmaf(w2, bf_lo(h2.y), acc[2]); acc[3] = fmaf(w2, bf_hi(h2.y), acc[3]);
        acc[4] = fmaf(w2, bf_lo(h2.z), acc[4]); acc[5] = fmaf(w2, bf_hi(h2.z), acc[5]);
        acc[6] = fmaf(w2, bf_lo(h2.w), acc[6]); acc[7] = fmaf(w2, bf_hi(h2.w), acc[7]);
        acc[0] = fmaf(w3, bf_lo(h3.x), acc[0]); acc[1] = fmaf(w3, bf_hi(h3.x), acc[1]);
        acc[2] = fmaf(w3, bf_lo(h3.y), acc[2]); acc[3] = fmaf(w3, bf_hi(h3.y), acc[3]);
        acc[4] = fmaf(w3, bf_lo(h3.z), acc[4]); acc[5] = fmaf(w3, bf_hi(h3.z), acc[5]);
        acc[6] = fmaf(w3, bf_lo(h3.w), acc[6]); acc[7] = fmaf(w3, bf_hi(h3.w), acc[7]);
        wsum += (w0 + w1) + (w2 + w3);
        i = ni; s0 = t0; s1 = t1; s2 = t2; s3 = t3;
        v0 = nv0; v1 = nv1; v2 = nv2; v3 = nv3;
        if (i >= cnt) break;
    }
    // ---- butterfly reduce-scatter over the 8 edge-slot groups ----
    int g0 = grp & 1, g1 = (grp >> 1) & 1, g2 = grp >> 2;
    float n0, n1, n2, n3;
    {
        float s, r;
        s = g0 ? acc[0] : acc[1]; r = __shfl_xor(s, 8);  n0 = (g0 ? acc[1] : acc[0]) + r;
        s = g0 ? acc[2] : acc[3]; r = __shfl_xor(s, 8);  n1 = (g0 ? acc[3] : acc[2]) + r;
        s = g0 ? acc[4] : acc[5]; r = __shfl_xor(s, 8);  n2 = (g0 ? acc[5] : acc[4]) + r;
        s = g0 ? acc[6] : acc[7]; r = __shfl_xor(s, 8);  n3 = (g0 ? acc[7] : acc[6]) + r;
    }
    float m0, m1;
    {
        float s, r;
        s = g1 ? n0 : n1; r = __shfl_xor(s, 16); m0 = (g1 ? n1 : n0) + r;
        s = g1 ? n2 : n3; r = __shfl_xor(s, 16); m1 = (g1 ? n3 : n2) + r;
    }
    float fin;
    {
        float s = g2 ? m0 : m1; float r = __shfl_xor(s, 32); fin = (g2 ? m1 : m0) + r;
    }
    wsum += __shfl_xor(wsum, 8); wsum += __shfl_xor(wsum, 16); wsum += __shfl_xor(wsum, 32);
    float inv = cnt > 0 ? 1.f / wsum : 0.f;
    float o = fin * inv + b1l[(c << 3) | grp];
    o = o > 0.f ? o : __expf(o) - 1.f;     // ELU: 1 exp per lane, all 64 lanes
    hsh[wv][(c << 3) | grp] = o;
    // ---- layer-2 node transform: out[c2] = sum_k h[k] * W2t[c2][k] ----
    int c2 = lane & 31, half = lane >> 5;
    const float4* hp = (const float4*)&hsh[wv][half * 32];
    const float4* wp = (const float4*)&W2t[c2][half * 32];
    float acc2 = 0.f;
    #pragma unroll
    for (int q = 0; q < 8; ++q) {
        float4 hv = hp[q];
        float4 w4 = wp[q];
        acc2 = fmaf(hv.x, w4.x, acc2); acc2 = fmaf(hv.y, w4.y, acc2);
        acc2 = fmaf(hv.z, w4.z, acc2); acc2 = fmaf(hv.w, w4.w, acc2);
    }
    acc2 += __shfl_xor(acc2, 32);          // lanes 0..31 (and 32..63) hold out[c2]
    float ps = acc2 * as2[c2];
    float pd = acc2 * ad2[c2];
    ps += __shfl_xor(ps, 1); ps += __shfl_xor(ps, 2); ps += __shfl_xor(ps, 4);
    ps += __shfl_xor(ps, 8); ps += __shfl_xor(ps, 16);
    pd += __shfl_xor(pd, 1); pd += __shfl_xor(pd, 2); pd += __shfl_xor(pd, 4);
    pd += __shfl_xor(pd, 8); pd += __shfl_xor(pd, 16);
    int row = b*ND0 + d;
    if (half == 0) ht2[(size_t)row*32 + c2] = acc2;   // coalesced 128 B
    if (lane == 0) { es2[row] = ps; ed2[row] = pd; }
}

// ---------------- layer 2 per-dst aggregation (4-deep pipeline) ------------
// Same XCD-pair batch pinning; grid padded to 7504 with chunk guard (7500%8!=0).
__global__ __launch_bounds__(256) void k7_agg2(
        const int* __restrict__ srcsort1, const int* __restrict__ cur1,
        const int* __restrict__ res1,
        const float* __restrict__ es2, const float* __restrict__ ed2,
        const float* __restrict__ ht2, const float* __restrict__ b2,
        float* __restrict__ outp) {
    int xcd = blockIdx.x & 7;
    int b = xcd >> 1;
    int chunk = (blockIdx.x >> 3) * 2 + (xcd & 1);
    if (chunk >= ND1/4) return;            // pad blocks (grid 7504)
    int d = chunk * 4 + (threadIdx.x >> 6);
    int lane = threadIdx.x & 63;
    int grp = lane >> 3;                   // edge slot 0..7
    int c = lane & 7;                      // channel quad: channels 4c..4c+3
    int dn = res1[d];
    float edv = ed2[b*ND0 + dn];
    int start = d * CAP;
    int cnt = cur1[d];
    const float* esb = es2 + (size_t)b*ND0;
    const float* htb = ht2 + (size_t)b*ND0*32;
    float ax = 0.f, ay = 0.f, az = 0.f, aw = 0.f, wsum = 0.f;
    int i = grp;
    bool v0 = i      < cnt, v1 = i + 8  < cnt,
         v2 = i + 16 < cnt, v3 = i + 24 < cnt;
    int s0 = v0 ? srcsort1[start + i]      : 0;
    int s1 = v1 ? srcsort1[start + i + 8]  : 0;
    int s2 = v2 ? srcsort1[start + i + 16] : 0;
    int s3 = v3 ? srcsort1[start + i + 24] : 0;
    for (;;) {
        float lg0 = esb[s0], lg1 = esb[s1], lg2 = esb[s2], lg3 = esb[s3];
        float4 h0 = *(const float4*)&htb[(size_t)s0*32 + c*4];
        float4 h1 = *(const float4*)&htb[(size_t)s1*32 + c*4];
        float4 h2 = *(const float4*)&htb[(size_t)s2*32 + c*4];
        float4 h3 = *(const float4*)&htb[(size_t)s3*32 + c*4];
        int ni = i + 32;
        bool nv0 = false, nv1 = false, nv2 = false, nv3 = false;
        int t0 = 0, t1 = 0, t2 = 0, t3 = 0;
        if (ni < cnt) {                    // wave-uniform: skip prefetch on final iter
            nv0 = true;            nv1 = ni + 8  < cnt;
            nv2 = ni + 16 < cnt;   nv3 = ni + 24 < cnt;
            t0 =       srcsort1[start + ni];
            t1 = nv1 ? srcsort1[start + ni + 8]  : 0;
            t2 = nv2 ? srcsort1[start + ni + 16] : 0;
            t3 = nv3 ? srcsort1[start + ni + 24] : 0;
        }
        lg0 += edv; lg1 += edv; lg2 += edv; lg3 += edv;
        lg0 = lg0 > 0.f ? lg0 : NEG * lg0;
        lg1 = lg1 > 0.f ? lg1 : NEG * lg1;
        lg2 = lg2 > 0.f ? lg2 : NEG * lg2;
        lg3 = lg3 > 0.f ? lg3 : NEG * lg3;
        float w0 = v0 ? __expf(lg0) : 0.f;
        float w1 = v1 ? __expf(lg1) : 0.f;
        float w2 = v2 ? __expf(lg2) : 0.f;
        float w3 = v3 ? __expf(lg3) : 0.f;
        ax = fmaf(w0, h0.x, ax); ay = fmaf(w0, h0.y, ay);
        az = fmaf(w0, h0.z, az); aw = fmaf(w0, h0.w, aw);
        ax = fmaf(w1, h1.x, ax); ay = fmaf(w1, h1.y, ay);
        az = fmaf(w1, h1.z, az); aw = fmaf(w1, h1.w, aw);
        ax = fmaf(w2, h2.x, ax); ay = fmaf(w2, h2.y, ay);
        az = fmaf(w2, h2.z, az); aw = fmaf(w2, h2.w, aw);
        ax = fmaf(w3, h3.x, ax); ay = fmaf(w3, h3.y, ay);
        az = fmaf(w3, h3.z, az); aw = fmaf(w3, h3.w, aw);
        wsum += (w0 + w1) + (w2 + w3);
        i = ni; s0 = t0; s1 = t1; s2 = t2; s3 = t3;
        v0 = nv0; v1 = nv1; v2 = nv2; v3 = nv3;
        if (i >= cnt) break;
    }
    ax += __shfl_xor(ax, 8); ax += __shfl_xor(ax, 16); ax += __shfl_xor(ax, 32);
    ay += __shfl_xor(ay, 8); ay += __shfl_xor(ay, 16); ay += __shfl_xor(ay, 32);
    az += __shfl_xor(az, 8); az += __shfl_xor(az, 16); az += __shfl_xor(az, 32);
    aw += __shfl_xor(aw, 8); aw += __shfl_xor(aw, 16); aw += __shfl_xor(aw, 32);
    wsum += __shfl_xor(wsum, 8); wsum += __shfl_xor(wsum, 16); wsum += __shfl_xor(wsum, 32);
    if (grp == 0) {
        float inv = cnt > 0 ? 1.f / wsum : 0.f;
        float4 bb = *(const float4*)&b2[c*4];
        float4 o;
        o.x = ax*inv + bb.x; o.y = ay*inv + bb.y;
        o.z = az*inv + bb.z; o.w = aw*inv + bb.w;
        *(float4*)&outp[((size_t)(b*ND1 + d))*32 + c*4] = o;
    }
}

extern "C" void kernel_launch(void* const* d_in, const int* in_sizes, int n_in,
                              void* d_out, int out_size, void* d_ws, size_t ws_size,
                              hipStream_t stream) {
    const float* x        = (const float*)d_in[0];
    const int*   n_id0    = (const int*)d_in[1];
    const int*   res0     = (const int*)d_in[2];
    const int*   esrc0    = (const int*)d_in[3];
    const int*   edst0    = (const int*)d_in[4];
    const int*   res1     = (const int*)d_in[5];
    const int*   esrc1    = (const int*)d_in[6];
    const int*   edst1    = (const int*)d_in[7];
    const float* W1       = (const float*)d_in[8];
    const float* a_src1   = (const float*)d_in[9];
    const float* a_dst1   = (const float*)d_in[10];
    const float* b1       = (const float*)d_in[11];
    const float* W2       = (const float*)d_in[12];
    const float* a_src2   = (const float*)d_in[13];
    const float* a_dst2   = (const float*)d_in[14];
    const float* b2       = (const float*)d_in[15];
    float* outp = (float*)d_out;

    char* base = (char*)d_ws;
    unsigned short* ht1b = (unsigned short*)base;            // 120000*64*2  = 15,360,000 B
    float* es1  = (float*)(base + 15360000);                 // 960,000 f
    float* ed1  = es1 + 960000;                              // 960,000 f
    float* ht2  = ed1 + 960000;                              // 1,920,000 f
    float* es2  = ht2 + 1920000;                             // 60,000 f
    float* ed2  = es2 + 60000;                               // 60,000 f
    // cur0|cur1 contiguous so one memsetAsync zeroes both
    int* cur0     = (int*)(ed2 + 60000);                     // 15000
    int* cur1     = cur0 + ND0;                              // 7500
    int* srcsort0 = cur1 + ND1;                              // 15000*64 = 960,000
    int* srcsort1 = srcsort0 + ND0*CAP;                      // 7500*64  = 480,000
    // total ~37 MB

    hipMemsetAsync(cur0, 0, (ND0 + ND1) * sizeof(int), stream);
    kA_gemm_scat<<<K1B + SB8, 256, 0, stream>>>(x, n_id0, W1, a_src1, a_dst1,
                                                ht1b, es1, ed1,
                                                esrc0, edst0, esrc1, edst1,
                                                cur0, cur1, srcsort0, srcsort1);
    k3_agg1_node2<<<NB*(ND0/4), 256, 0, stream>>>(srcsort0, cur0, res0, es1, ed1, ht1b, b1,
                                                  W2, a_src2, a_dst2, ht2, es2, ed2);
    k7_agg2<<<7504, 256, 0, stream>>>(srcsort1, cur1, res1, es2, ed2, ht2, b2, outp);
}

// Round 6
// 190.941 us; speedup vs baseline: 1.3045x; 1.0037x over previous
//
#include <hip/hip_runtime.h>

#define NB 4
#define NT 40000
#define NS0 30000
#define ND0 15000
#define NE0 360000
#define ND1 7500
#define NE1 180000
#define NEG 0.2f

#define CAP 64                            // bucket capacity per dst (avg deg 24)
#define K1B ((NB*NS0)/64)                 // 1875 GEMM blocks
#define SB8 ((NE0 + NE1 + 2047)/2048)     // 264 scatter blocks (8 edges/thread)

typedef __attribute__((ext_vector_type(8))) short bf8;
typedef __attribute__((ext_vector_type(4))) float f4;

__device__ __forceinline__ unsigned short f2bf(float f) {
    unsigned u = __float_as_uint(f);
    u += 0x7FFF + ((u >> 16) & 1);          // round-to-nearest-even
    return (unsigned short)(u >> 16);
}
// packed bf16 pair in a uint: low ushort = even channel, high = odd channel
__device__ __forceinline__ float bf_lo(unsigned u) { return __uint_as_float(u << 16); }
__device__ __forceinline__ float bf_hi(unsigned u) { return __uint_as_float(u & 0xFFFF0000u); }

// -------- fused: layer-1 MFMA GEMM + bucket scatter (CSR without scan) -----
// GEMM C-tile now exits via LDS bounce -> fully coalesced dwordx4 stores
// (kills the 2-byte partial-line write amplification: WRITE 55 -> ~28 MB).
// es/ed interleaved per row (esd1[row][h*2+{0,1}]) = one 64-B line per row.
__global__ __launch_bounds__(256) void kA_gemm_scat(
        const float* __restrict__ x, const int* __restrict__ n_id0,
        const float* __restrict__ W1, const float* __restrict__ a_src,
        const float* __restrict__ a_dst,
        unsigned short* __restrict__ ht1b, float* __restrict__ esd1,
        const int* __restrict__ esrc0, const int* __restrict__ edst0,
        const int* __restrict__ esrc1, const int* __restrict__ edst1,
        int* __restrict__ cur0, int* __restrict__ cur1,
        int* __restrict__ srcsort0, int* __restrict__ srcsort1) {
    __shared__ unsigned short xtb[64*72];
    __shared__ unsigned short wtb[64*72];
    __shared__ float asl[64], adl[64];
    if (blockIdx.x >= K1B) {                 // ---- scatter part (tail) ----
        int base = (blockIdx.x - K1B) * 2048 + threadIdx.x;
        #pragma unroll
        for (int p = 0; p < 8; ++p) {
            int t = base + p * 256;
            if (t < NE0) {
                int d = edst0[t];
                int pos = atomicAdd(&cur0[d], 1);
                if (pos < CAP) srcsort0[d*CAP + pos] = esrc0[t];
            } else if (t < NE0 + NE1) {
                int e = t - NE0;
                int d = edst1[e];
                int pos = atomicAdd(&cur1[d], 1);
                if (pos < CAP) srcsort1[d*CAP + pos] = esrc1[e];
            }
        }
        return;
    }
    // ---- GEMM part ----
    int bid = blockIdx.x;
    int t = threadIdx.x;
    {
        int k = t >> 2, nb = (t & 3) * 16;
        const float* wrow = &W1[k*64 + nb];
        #pragma unroll
        for (int j = 0; j < 16; j += 4) {
            float4 v = *(const float4*)&wrow[j];
            wtb[(nb+j+0)*72 + k] = f2bf(v.x);
            wtb[(nb+j+1)*72 + k] = f2bf(v.y);
            wtb[(nb+j+2)*72 + k] = f2bf(v.z);
            wtb[(nb+j+3)*72 + k] = f2bf(v.w);
        }
    }
    if (t < 64) { asl[t] = a_src[t]; adl[t] = a_dst[t]; }
    {
        // Cooperative gather: 4 consecutive lanes share one row (16 lines
        // per instruction instead of 64).
        int r   = t >> 2;
        int sub = t & 3;
        int row_s = bid * 64 + r;
        int bs = row_s / NS0;
        int ns = row_s - bs * NS0;
        const float* xrow = x + ((size_t)(bs * NT + n_id0[ns])) * 64;
        #pragma unroll
        for (int j = 0; j < 4; ++j) {
            int kf = (sub + j*4) * 4;
            float4 v = *(const float4*)&xrow[kf];
            ushort4 u;
            u.x = f2bf(v.x); u.y = f2bf(v.y); u.z = f2bf(v.z); u.w = f2bf(v.w);
            *(ushort4*)&xtb[r*72 + kf] = u;
        }
    }
    __syncthreads();
    int w = t >> 6, lane = t & 63, quad = lane >> 4, cl = lane & 15;
    int arow = 16*w + cl;
    bf8 a0 = *(const bf8*)&xtb[arow*72 + quad*8];        // A[m=cl][k=quad*8+j]
    bf8 a1 = *(const bf8*)&xtb[arow*72 + 32 + quad*8];   // k+32
    f4 acc[4];
    #pragma unroll
    for (int sub = 0; sub < 4; ++sub) {
        int n = sub*16 + cl;
        bf8 b0 = *(const bf8*)&wtb[n*72 + quad*8];       // B[k][n=cl]
        bf8 b1v = *(const bf8*)&wtb[n*72 + 32 + quad*8];
        f4 c = {0.f, 0.f, 0.f, 0.f};
        c = __builtin_amdgcn_mfma_f32_16x16x32_bf16(a0, b0, c, 0, 0, 0);
        c = __builtin_amdgcn_mfma_f32_16x16x32_bf16(a1, b1v, c, 0, 0, 0);
        acc[sub] = c;
    }
    // ---- LDS bounce: C-tile -> xtb (reuse) -> coalesced global ----
    __syncthreads();                       // all xtb/wtb LDS reads complete
    unsigned short* ob = xtb;              // 64 rows x 64 ushort (8 KB)
    #pragma unroll
    for (int sub = 0; sub < 4; ++sub)
        #pragma unroll
        for (int r = 0; r < 4; ++r)
            ob[(16*w + 4*quad + r)*64 + sub*16 + cl] = f2bf(acc[sub][r]);
    // es/ed epilogue (registers + 8B stores; one 64-B line per row)
    int rbase = bid*64 + 16*w + quad*4;
    #pragma unroll
    for (int r = 0; r < 4; ++r) {
        #pragma unroll
        for (int sub = 0; sub < 4; ++sub) {
            int col = sub*16 + cl;
            float ps = acc[sub][r] * asl[col];
            float pd = acc[sub][r] * adl[col];
            ps += __shfl_xor(ps, 1); ps += __shfl_xor(ps, 2); ps += __shfl_xor(ps, 4);
            pd += __shfl_xor(pd, 1); pd += __shfl_xor(pd, 2); pd += __shfl_xor(pd, 4);
            if ((cl & 7) == 0) {
                int h = sub*2 + (cl >> 3);
                *(float2*)&esd1[(size_t)(rbase + r)*16 + h*2] = make_float2(ps, pd);
            }
        }
    }
    __syncthreads();                       // ob fully written
    {
        int row = t >> 3;                  // 0..31
        int c8  = t & 7;                   // 16-B chunk -> superbank = c8 (conflict-free)
        #pragma unroll
        for (int rep = 0; rep < 2; ++rep) {
            int rr2 = row + rep*32;
            uint4 v = *(const uint4*)&ob[rr2*64 + c8*8];
            *(uint4*)&ht1b[((size_t)(bid*64 + rr2))*64 + c8*8] = v;   // 1024 B/wave-inst
        }
    }
}

// -------- fused: layer-1 aggregation + layer-2 node transform (PERSISTENT) -
// 2048 blocks (8/CU), each stages W2 ONCE then loops over dst-chunks with no
// in-loop barrier (hsh handoff is same-wave). Kills the 15000-block staging
// churn (59 stagings/CU -> 8) and lifts occupancy 60% -> ~full.
__global__ __launch_bounds__(256) void k3_agg1_node2(
        const int* __restrict__ srcsort0, const int* __restrict__ cur0,
        const int* __restrict__ res0,
        const float* __restrict__ esd1,
        const unsigned short* __restrict__ ht1b, const float* __restrict__ b1,
        const float* __restrict__ W2, const float* __restrict__ a_src2,
        const float* __restrict__ a_dst2,
        float* __restrict__ ht2, float* __restrict__ esd2) {
    __shared__ float W2t[32][68];          // W2t[c2][k] = W2[k][c2]
    __shared__ float as2[32], ad2[32];
    __shared__ float b1l[64];
    __shared__ float hsh[4][64];           // per-wave h(d)
    int t = threadIdx.x;
    {   // coalesced W2 read (8 KB) + transposed LDS write (once per block)
        float4 v0 = *(const float4*)&W2[t*8];
        float4 v1 = *(const float4*)&W2[t*8 + 4];
        int k = t >> 2, c = (t & 3) * 8;
        W2t[c+0][k] = v0.x; W2t[c+1][k] = v0.y; W2t[c+2][k] = v0.z; W2t[c+3][k] = v0.w;
        W2t[c+4][k] = v1.x; W2t[c+5][k] = v1.y; W2t[c+6][k] = v1.z; W2t[c+7][k] = v1.w;
    }
    if (t < 32) { as2[t] = a_src2[t]; ad2[t] = a_dst2[t]; }
    if (t < 64) b1l[t] = b1[t];
    __syncthreads();                       // only barrier in the kernel
    int xcd = blockIdx.x & 7;
    int b = xcd >> 1;                      // batch pinned to XCD pair
    int pb2 = (blockIdx.x >> 3) * 2 + (xcd & 1);     // 0..511 within batch
    int wv = t >> 6;
    int lane = t & 63;
    int grp = lane >> 3;                   // edge slot 0..7
    int c = lane & 7;                      // head index; channels 8c..8c+7
    const float* esb = esd1 + (size_t)b*NS0*16;
    const unsigned short* htb = ht1b + (size_t)b*NS0*64;
    for (int chunk = pb2; chunk < ND0/4; chunk += 512) {
        int d = chunk * 4 + wv;
        int dn = res0[d];
        float edv = esb[(size_t)dn*16 + c*2 + 1];
        int start = d * CAP;
        int cnt = cur0[d];
        float acc[8] = {};
        float wsum = 0.f;
        int i = grp;
        bool v0 = i      < cnt, v1 = i + 8  < cnt,
             v2 = i + 16 < cnt, v3 = i + 24 < cnt;
        int s0 = v0 ? srcsort0[start + i]      : 0;
        int s1 = v1 ? srcsort0[start + i + 8]  : 0;
        int s2 = v2 ? srcsort0[start + i + 16] : 0;
        int s3 = v3 ? srcsort0[start + i + 24] : 0;
        for (;;) {
            float e0 = esb[s0*16 + c*2], e1 = esb[s1*16 + c*2];
            float e2 = esb[s2*16 + c*2], e3 = esb[s3*16 + c*2];
            uint4 h0 = *(const uint4*)&htb[(size_t)s0*64 + c*8];
            uint4 h1 = *(const uint4*)&htb[(size_t)s1*64 + c*8];
            uint4 h2 = *(const uint4*)&htb[(size_t)s2*64 + c*8];
            uint4 h3 = *(const uint4*)&htb[(size_t)s3*64 + c*8];
            int ni = i + 32;
            bool nv0 = false, nv1 = false, nv2 = false, nv3 = false;
            int t0 = 0, t1 = 0, t2 = 0, t3 = 0;
            if (ni < cnt) {                // wave-uniform: skip prefetch on final iter
                nv0 = true;            nv1 = ni + 8  < cnt;
                nv2 = ni + 16 < cnt;   nv3 = ni + 24 < cnt;
                t0 =       srcsort0[start + ni];
                t1 = nv1 ? srcsort0[start + ni + 8]  : 0;
                t2 = nv2 ? srcsort0[start + ni + 16] : 0;
                t3 = nv3 ? srcsort0[start + ni + 24] : 0;
            }
            e0 += edv; e1 += edv; e2 += edv; e3 += edv;
            e0 = e0 > 0.f ? e0 : NEG * e0;
            e1 = e1 > 0.f ? e1 : NEG * e1;
            e2 = e2 > 0.f ? e2 : NEG * e2;
            e3 = e3 > 0.f ? e3 : NEG * e3;
            float w0 = v0 ? __expf(e0) : 0.f;
            float w1 = v1 ? __expf(e1) : 0.f;
            float w2 = v2 ? __expf(e2) : 0.f;
            float w3 = v3 ? __expf(e3) : 0.f;
            acc[0] = fmaf(w0, bf_lo(h0.x), acc[0]); acc[1] = fmaf(w0, bf_hi(h0.x), acc[1]);
            acc[2] = fmaf(w0, bf_lo(h0.y), acc[2]); acc[3] = fmaf(w0, bf_hi(h0.y), acc[3]);
            acc[4] = fmaf(w0, bf_lo(h0.z), acc[4]); acc[5] = fmaf(w0, bf_hi(h0.z), acc[5]);
            acc[6] = fmaf(w0, bf_lo(h0.w), acc[6]); acc[7] = fmaf(w0, bf_hi(h0.w), acc[7]);
            acc[0] = fmaf(w1, bf_lo(h1.x), acc[0]); acc[1] = fmaf(w1, bf_hi(h1.x), acc[1]);
            acc[2] = fmaf(w1, bf_lo(h1.y), acc[2]); acc[3] = fmaf(w1, bf_hi(h1.y), acc[3]);
            acc[4] = fmaf(w1, bf_lo(h1.z), acc[4]); acc[5] = fmaf(w1, bf_hi(h1.z), acc[5]);
            acc[6] = fmaf(w1, bf_lo(h1.w), acc[6]); acc[7] = fmaf(w1, bf_hi(h1.w), acc[7]);
            acc[0] = fmaf(w2, bf_lo(h2.x), acc[0]); acc[1] = fmaf(w2, bf_hi(h2.x), acc[1]);
            acc[2] = fmaf(w2, bf_lo(h2.y), acc[2]); acc[3] = fmaf(w2, bf_hi(h2.y), acc[3]);
            acc[4] = fmaf(w2, bf_lo(h2.z), acc[4]); acc[5] = fmaf(w2, bf_hi(h2.z), acc[5]);
            acc[6] = fmaf(w2, bf_lo(h2.w), acc[6]); acc[7] = fmaf(w2, bf_hi(h2.w), acc[7]);
            acc[0] = fmaf(w3, bf_lo(h3.x), acc[0]); acc[1] = fmaf(w3, bf_hi(h3.x), acc[1]);
            acc[2] = fmaf(w3, bf_lo(h3.y), acc[2]); acc[3] = fmaf(w3, bf_hi(h3.y), acc[3]);
            acc[4] = fmaf(w3, bf_lo(h3.z), acc[4]); acc[5] = fmaf(w3, bf_hi(h3.z), acc[5]);
            acc[6] = fmaf(w3, bf_lo(h3.w), acc[6]); acc[7] = fmaf(w3, bf_hi(h3.w), acc[7]);
            wsum += (w0 + w1) + (w2 + w3);
            i = ni; s0 = t0; s1 = t1; s2 = t2; s3 = t3;
            v0 = nv0; v1 = nv1; v2 = nv2; v3 = nv3;
            if (i >= cnt) break;
        }
        // ---- butterfly reduce-scatter over the 8 edge-slot groups ----
        int g0 = grp & 1, g1 = (grp >> 1) & 1, g2 = grp >> 2;
        float n0, n1, n2, n3;
        {
            float s, r;
            s = g0 ? acc[0] : acc[1]; r = __shfl_xor(s, 8);  n0 = (g0 ? acc[1] : acc[0]) + r;
            s = g0 ? acc[2] : acc[3]; r = __shfl_xor(s, 8);  n1 = (g0 ? acc[3] : acc[2]) + r;
            s = g0 ? acc[4] : acc[5]; r = __shfl_xor(s, 8);  n2 = (g0 ? acc[5] : acc[4]) + r;
            s = g0 ? acc[6] : acc[7]; r = __shfl_xor(s, 8);  n3 = (g0 ? acc[7] : acc[6]) + r;
        }
        float m0, m1;
        {
            float s, r;
            s = g1 ? n0 : n1; r = __shfl_xor(s, 16); m0 = (g1 ? n1 : n0) + r;
            s = g1 ? n2 : n3; r = __shfl_xor(s, 16); m1 = (g1 ? n3 : n2) + r;
        }
        float fin;
        {
            float s = g2 ? m0 : m1; float r = __shfl_xor(s, 32); fin = (g2 ? m1 : m0) + r;
        }
        wsum += __shfl_xor(wsum, 8); wsum += __shfl_xor(wsum, 16); wsum += __shfl_xor(wsum, 32);
        float inv = cnt > 0 ? 1.f / wsum : 0.f;
        float o = fin * inv + b1l[(c << 3) | grp];
        o = o > 0.f ? o : __expf(o) - 1.f;     // ELU: 1 exp/lane, all 64 lanes
        hsh[wv][(c << 3) | grp] = o;
        // hsh[wv] written+read by the SAME wave -> lgkmcnt ordering suffices.
        // ---- layer-2 node transform: out[c2] = sum_k h[k] * W2t[c2][k] ----
        int c2 = lane & 31, half = lane >> 5;
        const float4* hp = (const float4*)&hsh[wv][half * 32];
        const float4* wp = (const float4*)&W2t[c2][half * 32];
        float acc2 = 0.f;
        #pragma unroll
        for (int q = 0; q < 8; ++q) {
            float4 hv = hp[q];
            float4 w4 = wp[q];
            acc2 = fmaf(hv.x, w4.x, acc2); acc2 = fmaf(hv.y, w4.y, acc2);
            acc2 = fmaf(hv.z, w4.z, acc2); acc2 = fmaf(hv.w, w4.w, acc2);
        }
        acc2 += __shfl_xor(acc2, 32);
        float ps = acc2 * as2[c2];
        float pd = acc2 * ad2[c2];
        ps += __shfl_xor(ps, 1); ps += __shfl_xor(ps, 2); ps += __shfl_xor(ps, 4);
        ps += __shfl_xor(ps, 8); ps += __shfl_xor(ps, 16);
        pd += __shfl_xor(pd, 1); pd += __shfl_xor(pd, 2); pd += __shfl_xor(pd, 4);
        pd += __shfl_xor(pd, 8); pd += __shfl_xor(pd, 16);
        int row = b*ND0 + d;
        if (half == 0) ht2[(size_t)row*32 + c2] = acc2;   // coalesced 128 B
        if (lane == 0) *(float2*)&esd2[(size_t)row*2] = make_float2(ps, pd);
    }
}

// ---------------- layer 2 per-dst aggregation (PERSISTENT) -----------------
__global__ __launch_bounds__(256) void k7_agg2(
        const int* __restrict__ srcsort1, const int* __restrict__ cur1,
        const int* __restrict__ res1,
        const float* __restrict__ esd2,
        const float* __restrict__ ht2, const float* __restrict__ b2,
        float* __restrict__ outp) {
    int xcd = blockIdx.x & 7;
    int b = xcd >> 1;
    int pb2 = (blockIdx.x >> 3) * 2 + (xcd & 1);     // 0..511 within batch
    int lane = threadIdx.x & 63;
    int wv = threadIdx.x >> 6;
    int grp = lane >> 3;                   // edge slot 0..7
    int c = lane & 7;                      // channel quad: channels 4c..4c+3
    const float* esb = esd2 + (size_t)b*ND0*2;
    const float* htb = ht2 + (size_t)b*ND0*32;
    for (int chunk = pb2; chunk < ND1/4; chunk += 512) {
        int d = chunk * 4 + wv;
        int dn = res1[d];
        float edv = esb[(size_t)dn*2 + 1];
        int start = d * CAP;
        int cnt = cur1[d];
        float ax = 0.f, ay = 0.f, az = 0.f, aw = 0.f, wsum = 0.f;
        int i = grp;
        bool v0 = i      < cnt, v1 = i + 8  < cnt,
             v2 = i + 16 < cnt, v3 = i + 24 < cnt;
        int s0 = v0 ? srcsort1[start + i]      : 0;
        int s1 = v1 ? srcsort1[start + i + 8]  : 0;
        int s2 = v2 ? srcsort1[start + i + 16] : 0;
        int s3 = v3 ? srcsort1[start + i + 24] : 0;
        for (;;) {
            float lg0 = esb[s0*2], lg1 = esb[s1*2], lg2 = esb[s2*2], lg3 = esb[s3*2];
            float4 h0 = *(const float4*)&htb[(size_t)s0*32 + c*4];
            float4 h1 = *(const float4*)&htb[(size_t)s1*32 + c*4];
            float4 h2 = *(const float4*)&htb[(size_t)s2*32 + c*4];
            float4 h3 = *(const float4*)&htb[(size_t)s3*32 + c*4];
            int ni = i + 32;
            bool nv0 = false, nv1 = false, nv2 = false, nv3 = false;
            int t0 = 0, t1 = 0, t2 = 0, t3 = 0;
            if (ni < cnt) {                // wave-uniform: skip prefetch on final iter
                nv0 = true;            nv1 = ni + 8  < cnt;
                nv2 = ni + 16 < cnt;   nv3 = ni + 24 < cnt;
                t0 =       srcsort1[start + ni];
                t1 = nv1 ? srcsort1[start + ni + 8]  : 0;
                t2 = nv2 ? srcsort1[start + ni + 16] : 0;
                t3 = nv3 ? srcsort1[start + ni + 24] : 0;
            }
            lg0 += edv; lg1 += edv; lg2 += edv; lg3 += edv;
            lg0 = lg0 > 0.f ? lg0 : NEG * lg0;
            lg1 = lg1 > 0.f ? lg1 : NEG * lg1;
            lg2 = lg2 > 0.f ? lg2 : NEG * lg2;
            lg3 = lg3 > 0.f ? lg3 : NEG * lg3;
            float w0 = v0 ? __expf(lg0) : 0.f;
            float w1 = v1 ? __expf(lg1) : 0.f;
            float w2 = v2 ? __expf(lg2) : 0.f;
            float w3 = v3 ? __expf(lg3) : 0.f;
            ax = fmaf(w0, h0.x, ax); ay = fmaf(w0, h0.y, ay);
            az = fmaf(w0, h0.z, az); aw = fmaf(w0, h0.w, aw);
            ax = fmaf(w1, h1.x, ax); ay = fmaf(w1, h1.y, ay);
            az = fmaf(w1, h1.z, az); aw = fmaf(w1, h1.w, aw);
            ax = fmaf(w2, h2.x, ax); ay = fmaf(w2, h2.y, ay);
            az = fmaf(w2, h2.z, az); aw = fmaf(w2, h2.w, aw);
            ax = fmaf(w3, h3.x, ax); ay = fmaf(w3, h3.y, ay);
            az = fmaf(w3, h3.z, az); aw = fmaf(w3, h3.w, aw);
            wsum += (w0 + w1) + (w2 + w3);
            i = ni; s0 = t0; s1 = t1; s2 = t2; s3 = t3;
            v0 = nv0; v1 = nv1; v2 = nv2; v3 = nv3;
            if (i >= cnt) break;
        }
        ax += __shfl_xor(ax, 8); ax += __shfl_xor(ax, 16); ax += __shfl_xor(ax, 32);
        ay += __shfl_xor(ay, 8); ay += __shfl_xor(ay, 16); ay += __shfl_xor(ay, 32);
        az += __shfl_xor(az, 8); az += __shfl_xor(az, 16); az += __shfl_xor(az, 32);
        aw += __shfl_xor(aw, 8); aw += __shfl_xor(aw, 16); aw += __shfl_xor(aw, 32);
        wsum += __shfl_xor(wsum, 8); wsum += __shfl_xor(wsum, 16); wsum += __shfl_xor(wsum, 32);
        if (grp == 0) {
            float inv = cnt > 0 ? 1.f / wsum : 0.f;
            float4 bb = *(const float4*)&b2[c*4];
            float4 o;
            o.x = ax*inv + bb.x; o.y = ay*inv + bb.y;
            o.z = az*inv + bb.z; o.w = aw*inv + bb.w;
            *(float4*)&outp[((size_t)(b*ND1 + d))*32 + c*4] = o;
        }
    }
}

extern "C" void kernel_launch(void* const* d_in, const int* in_sizes, int n_in,
                              void* d_out, int out_size, void* d_ws, size_t ws_size,
                              hipStream_t stream) {
    const float* x        = (const float*)d_in[0];
    const int*   n_id0    = (const int*)d_in[1];
    const int*   res0     = (const int*)d_in[2];
    const int*   esrc0    = (const int*)d_in[3];
    const int*   edst0    = (const int*)d_in[4];
    const int*   res1     = (const int*)d_in[5];
    const int*   esrc1    = (const int*)d_in[6];
    const int*   edst1    = (const int*)d_in[7];
    const float* W1       = (const float*)d_in[8];
    const float* a_src1   = (const float*)d_in[9];
    const float* a_dst1   = (const float*)d_in[10];
    const float* b1       = (const float*)d_in[11];
    const float* W2       = (const float*)d_in[12];
    const float* a_src2   = (const float*)d_in[13];
    const float* a_dst2   = (const float*)d_in[14];
    const float* b2       = (const float*)d_in[15];
    float* outp = (float*)d_out;

    char* base = (char*)d_ws;
    unsigned short* ht1b = (unsigned short*)base;            // 120000*64*2  = 15,360,000 B
    float* esd1 = (float*)(base + 15360000);                 // 120000*16 = 1,920,000 f (es|ed interleaved)
    float* ht2  = esd1 + 1920000;                            // 1,920,000 f
    float* esd2 = ht2 + 1920000;                             // 120,000 f (es2|ed2 interleaved)
    // cur0|cur1 contiguous so one memsetAsync zeroes both
    int* cur0     = (int*)(esd2 + 120000);                   // 15000
    int* cur1     = cur0 + ND0;                              // 7500
    int* srcsort0 = cur1 + ND1;                              // 15000*64 = 960,000
    int* srcsort1 = srcsort0 + ND0*CAP;                      // 7500*64  = 480,000
    // total ~37 MB

    hipMemsetAsync(cur0, 0, (ND0 + ND1) * sizeof(int), stream);
    kA_gemm_scat<<<K1B + SB8, 256, 0, stream>>>(x, n_id0, W1, a_src1, a_dst1,
                                                ht1b, esd1,
                                                esrc0, edst0, esrc1, edst1,
                                                cur0, cur1, srcsort0, srcsort1);
    k3_agg1_node2<<<2048, 256, 0, stream>>>(srcsort0, cur0, res0, esd1, ht1b, b1,
                                            W2, a_src2, a_dst2, ht2, esd2);
    k7_agg2<<<2048, 256, 0, stream>>>(srcsort1, cur1, res1, esd2, ht2, b2, outp);
}